// Round 4
// baseline (587.092 us; speedup 1.0000x reference)
//
#include <hip/hip_runtime.h>

typedef unsigned int u32;
typedef _Float16 f16;
typedef __attribute__((ext_vector_type(8))) _Float16 half8;
typedef __attribute__((ext_vector_type(2))) _Float16 half2_t;
typedef __attribute__((ext_vector_type(4))) float f32x4;

#define D_IN 128
#define D_HID 128
#define D_OUT 16

// ---------------- preprocessing ----------------

// flag: 1 if edge_index is int32 layout, 0 if int64 (odd words all zero).
__global__ __launch_bounds__(256) void detect_k(const int* __restrict__ ei,
                                                u32* __restrict__ flag, int n) {
    int i = blockIdx.x * 256 + threadIdx.x;
    if (i < n && (i & 1) && ei[i] != 0) atomicOr(flag, 1u);
}

__device__ inline int load_row(const int* ei, u32 f, int e, int E) {
    return f ? ei[e] : ei[2 * e];
}
__device__ inline int load_col(const int* ei, u32 f, int e, int E) {
    return f ? ei[E + e] : ei[2 * E + 2 * e];
}
__device__ inline int clampi(int v, int n) {
    v = v < 0 ? 0 : v;
    return v >= n ? n - 1 : v;
}

__global__ __launch_bounds__(256) void count_rows(const int* __restrict__ ei,
                                                  const u32* __restrict__ flag,
                                                  u32* __restrict__ cnt, int E, int N) {
    int e = blockIdx.x * 256 + threadIdx.x;
    if (e >= E) return;
    u32 f = *flag;
    int r = clampi(load_row(ei, f, e, E), N);
    atomicAdd(&cnt[r], 1u);
}

__global__ __launch_bounds__(256) void dinv_k(const u32* __restrict__ cnt,
                                              float* __restrict__ dinv, int n) {
    int i = blockIdx.x * 256 + threadIdx.x;
    if (i < n) dinv[i] = rsqrtf((float)(cnt[i] + 1u));  // +1 self loop
}

__global__ __launch_bounds__(256) void scan1(const u32* __restrict__ cnt,
                                             u32* __restrict__ excl,
                                             u32* __restrict__ partial, int n) {
    __shared__ u32 sm[256];
    int tid = threadIdx.x;
    int i = blockIdx.x * 256 + tid;
    u32 v = (i < n) ? cnt[i] : 0u;
    sm[tid] = v;
    __syncthreads();
    for (int off = 1; off < 256; off <<= 1) {
        u32 t = (tid >= off) ? sm[tid - off] : 0u;
        __syncthreads();
        sm[tid] += t;
        __syncthreads();
    }
    if (i < n) excl[i] = sm[tid] - v;
    if (tid == 255) partial[blockIdx.x] = sm[255];
}

__global__ __launch_bounds__(512) void scan2(u32* __restrict__ partial, int nb) {
    __shared__ u32 sm[512];
    int tid = threadIdx.x;
    u32 v = (tid < nb) ? partial[tid] : 0u;
    sm[tid] = v;
    __syncthreads();
    for (int off = 1; off < 512; off <<= 1) {
        u32 t = (tid >= off) ? sm[tid - off] : 0u;
        __syncthreads();
        sm[tid] += t;
        __syncthreads();
    }
    if (tid < nb) partial[tid] = sm[tid] - v;
}

__global__ __launch_bounds__(256) void scan3(u32* __restrict__ excl,
                                             const u32* __restrict__ partial,
                                             int n, int E) {
    int i = blockIdx.x * 256 + threadIdx.x;
    if (i < n) excl[i] += partial[blockIdx.x];
    if (i == 0) excl[n] = (u32)E;
}

// Windowed CSR scatter: only rows in [lo,hi) are written this pass, so the
// write target region (~E/8 * 4B = 800KB) stays L2-resident and line
// writebacks merge; cursor atomics hit a hot 50KB window.
__global__ __launch_bounds__(256) void scatter_win(const int* __restrict__ ei,
                                                   const u32* __restrict__ flag,
                                                   const u32* __restrict__ row_start,
                                                   u32* __restrict__ cursor,
                                                   u32* __restrict__ ecol,
                                                   int E, int N, int lo, int hi) {
    int e = blockIdx.x * 256 + threadIdx.x;
    if (e >= E) return;
    u32 f = *flag;
    int r = clampi(load_row(ei, f, e, E), N);
    if (r < lo || r >= hi) return;
    int c = clampi(load_col(ei, f, e, E), N);
    u32 pos = row_start[r] + atomicAdd(&cursor[r], 1u);
    if (pos < (u32)E) ecol[pos] = (u32)c;
}

// Split fp32 W [128 x (ntiles*16)] into hi/lo f16 MFMA B-fragments.
__global__ __launch_bounds__(256) void reformat_w(const float* __restrict__ W,
                                                  f16* __restrict__ Wh,
                                                  f16* __restrict__ Wl, int ntiles) {
    int idx = blockIdx.x * 256 + threadIdx.x;
    int total = 4 * ntiles * 64;
    if (idx >= total) return;
    int lane = idx & 63;
    int st = idx >> 6;
    int t = st % ntiles;
    int s = st / ntiles;
    int Nc = ntiles * 16;
    int n = t * 16 + (lane & 15);
    int kb = lane >> 4;
    half8 vh, vl;
#pragma unroll
    for (int j = 0; j < 8; j++) {
        float w = W[(size_t)(s * 32 + kb * 8 + j) * Nc + n];
        f16 hi = (f16)w;
        f16 lo = (f16)(w - (float)hi);
        vh[j] = hi;
        vl[j] = lo;
    }
    *(half8*)(Wh + (size_t)idx * 8) = vh;
    *(half8*)(Wl + (size_t)idx * 8) = vl;
}

// ---------------- GEMMs (f16 MFMA 16x16x32, fp32-accurate via splits) --------

// Layer 1: A fp32 [M x 128]; 3 MFMAs; epilogue scales row rr by dinv[rr]
// so the stored table is h' = (x@W1)*dinv  (norm folded into storage).
__global__ __launch_bounds__(256) void gemm128_l1(const float* __restrict__ A,
                                                  const f16* __restrict__ Wh,
                                                  const f16* __restrict__ Wl,
                                                  const float* __restrict__ dinv,
                                                  f16* __restrict__ H, int M) {
    int wave = threadIdx.x >> 6, lane = threadIdx.x & 63;
    int mbase = blockIdx.x * 64 + wave * 16;
    int mload = mbase + (lane & 15);
    if (mload >= M) mload = M - 1;
    int kq = lane >> 4;
    f32x4 acc[8];
#pragma unroll
    for (int t = 0; t < 8; t++) acc[t] = (f32x4){0.f, 0.f, 0.f, 0.f};
#pragma unroll
    for (int s = 0; s < 4; s++) {
        const float* ap = A + (size_t)mload * 128 + s * 32 + kq * 8;
        half8 ah, al;
#pragma unroll
        for (int j = 0; j < 8; j++) {
            float v = ap[j];
            f16 hi = (f16)v;
            ah[j] = hi;
            al[j] = (f16)(v - (float)hi);
        }
#pragma unroll
        for (int t = 0; t < 8; t++) {
            half8 bh = *(const half8*)(Wh + (size_t)((s * 8 + t) * 64 + lane) * 8);
            half8 bl = *(const half8*)(Wl + (size_t)((s * 8 + t) * 64 + lane) * 8);
            acc[t] = __builtin_amdgcn_mfma_f32_16x16x32_f16(ah, bh, acc[t], 0, 0, 0);
            acc[t] = __builtin_amdgcn_mfma_f32_16x16x32_f16(ah, bl, acc[t], 0, 0, 0);
            acc[t] = __builtin_amdgcn_mfma_f32_16x16x32_f16(al, bh, acc[t], 0, 0, 0);
        }
    }
    int coln = lane & 15;
    int rbase = mbase + ((lane >> 4) << 2);
    float dsc[4];
#pragma unroll
    for (int i = 0; i < 4; i++) {
        int rr = rbase + i;
        dsc[i] = dinv[rr < M ? rr : M - 1];
    }
#pragma unroll
    for (int t = 0; t < 8; t++) {
#pragma unroll
        for (int i = 0; i < 4; i++) {
            int rr = rbase + i;
            if (rr < M) H[(size_t)rr * 128 + t * 16 + coln] = (f16)(acc[t][i] * dsc[i]);
        }
    }
}

// Layer 2: A f16 (pre-scaled act') [M x 128]; 2 MFMAs; output inherits the
// dinv row-scale automatically ((act*dinv)@W = (act@W)*dinv). No epilogue scale.
__global__ __launch_bounds__(256) void gemm128_l2(const f16* __restrict__ A,
                                                  const f16* __restrict__ Wh,
                                                  const f16* __restrict__ Wl,
                                                  f16* __restrict__ H, int M) {
    int wave = threadIdx.x >> 6, lane = threadIdx.x & 63;
    int mbase = blockIdx.x * 64 + wave * 16;
    int mload = mbase + (lane & 15);
    if (mload >= M) mload = M - 1;
    int kq = lane >> 4;
    f32x4 acc[8];
#pragma unroll
    for (int t = 0; t < 8; t++) acc[t] = (f32x4){0.f, 0.f, 0.f, 0.f};
#pragma unroll
    for (int s = 0; s < 4; s++) {
        half8 a = *(const half8*)(A + (size_t)mload * 128 + s * 32 + kq * 8);
#pragma unroll
        for (int t = 0; t < 8; t++) {
            half8 bh = *(const half8*)(Wh + (size_t)((s * 8 + t) * 64 + lane) * 8);
            half8 bl = *(const half8*)(Wl + (size_t)((s * 8 + t) * 64 + lane) * 8);
            acc[t] = __builtin_amdgcn_mfma_f32_16x16x32_f16(a, bh, acc[t], 0, 0, 0);
            acc[t] = __builtin_amdgcn_mfma_f32_16x16x32_f16(a, bl, acc[t], 0, 0, 0);
        }
    }
    int coln = lane & 15;
    int rbase = mbase + ((lane >> 4) << 2);
#pragma unroll
    for (int t = 0; t < 8; t++) {
#pragma unroll
        for (int i = 0; i < 4; i++) {
            int rr = rbase + i;
            if (rr < M) H[(size_t)rr * 128 + t * 16 + coln] = (f16)acc[t][i];
        }
    }
}

// Layer 3: A f16 (pre-scaled) [M x 128] -> H3' f16 [M x 16].
__global__ __launch_bounds__(256) void gemm16(const f16* __restrict__ A,
                                              const f16* __restrict__ Wh,
                                              const f16* __restrict__ Wl,
                                              f16* __restrict__ H, int M) {
    int wave = threadIdx.x >> 6, lane = threadIdx.x & 63;
    int mbase = blockIdx.x * 64 + wave * 16;
    int mload = mbase + (lane & 15);
    if (mload >= M) mload = M - 1;
    int kq = lane >> 4;
    f32x4 acc = (f32x4){0.f, 0.f, 0.f, 0.f};
#pragma unroll
    for (int s = 0; s < 4; s++) {
        half8 a = *(const half8*)(A + (size_t)mload * 128 + s * 32 + kq * 8);
        half8 bh = *(const half8*)(Wh + (size_t)(s * 64 + lane) * 8);
        half8 bl = *(const half8*)(Wl + (size_t)(s * 64 + lane) * 8);
        acc = __builtin_amdgcn_mfma_f32_16x16x32_f16(a, bh, acc, 0, 0, 0);
        acc = __builtin_amdgcn_mfma_f32_16x16x32_f16(a, bl, acc, 0, 0, 0);
    }
    int coln = lane & 15;
    int rbase = mbase + ((lane >> 4) << 2);
#pragma unroll
    for (int i = 0; i < 4; i++) {
        int rr = rbase + i;
        if (rr < M) H[(size_t)rr * 16 + coln] = (f16)acc[i];
    }
}

// ---------------- aggregation ----------------
// Feature-quartered, XCD-affine: quarter q = blockIdx&3 rides the round-robin
// block->XCD mapping so each XCD's gather working set is ~6.4MB (one quarter of
// the h' table) instead of 25.6MB. A 16-lane group gathers exactly one 64B line
// (32 f16 features) per edge. out = relu(dinv[r]*(sum h'[c] + h'[r]) + b)*dinv[r].
__global__ __launch_bounds__(256) void agg128_q(const f16* __restrict__ h,
                                                const u32* __restrict__ ecol,
                                                const u32* __restrict__ row_start,
                                                const float* __restrict__ dinv,
                                                const float* __restrict__ bias,
                                                f16* __restrict__ out, int M) {
    int q = blockIdx.x & 3;
    int rb = blockIdx.x >> 2;
    int g = threadIdx.x >> 4;
    int l = threadIdx.x & 15;
    int r = rb * 16 + g;
    if (r >= M) return;
    int fo = q * 16 + l;  // half2 offset within row (64 half2/row)
    const half2_t* hp = (const half2_t*)h;
    u32 beg = row_start[r], end = row_start[r + 1];
    float ax0 = 0, ay0 = 0, ax1 = 0, ay1 = 0, ax2 = 0, ay2 = 0, ax3 = 0, ay3 = 0;
    u32 e = beg;
    for (; e + 4 <= end; e += 4) {
        u32 c0 = ecol[e], c1 = ecol[e + 1], c2 = ecol[e + 2], c3 = ecol[e + 3];
        half2_t v0 = hp[(size_t)c0 * 64 + fo];
        half2_t v1 = hp[(size_t)c1 * 64 + fo];
        half2_t v2 = hp[(size_t)c2 * 64 + fo];
        half2_t v3 = hp[(size_t)c3 * 64 + fo];
        ax0 += (float)v0[0]; ay0 += (float)v0[1];
        ax1 += (float)v1[0]; ay1 += (float)v1[1];
        ax2 += (float)v2[0]; ay2 += (float)v2[1];
        ax3 += (float)v3[0]; ay3 += (float)v3[1];
    }
    for (; e < end; ++e) {
        u32 c = ecol[e];
        half2_t v = hp[(size_t)c * 64 + fo];
        ax0 += (float)v[0]; ay0 += (float)v[1];
    }
    half2_t vs = hp[(size_t)r * 64 + fo];
    float dr = dinv[r];
    float2 bb = ((const float2*)bias)[fo];
    float ax = (((ax0 + ax1) + (ax2 + ax3)) + (float)vs[0]) * dr + bb.x;
    float ay = (((ay0 + ay1) + (ay2 + ay3)) + (float)vs[1]) * dr + bb.y;
    ax = fmaxf(ax, 0.f) * dr;  // pre-scale for next layer's gather
    ay = fmaxf(ay, 0.f) * dr;
    half2_t o;
    o[0] = (f16)ax;
    o[1] = (f16)ay;
    ((half2_t*)out)[(size_t)r * 64 + fo] = o;
}

// 16 lanes per row; h3' is pre-scaled; fused bias + log_softmax; fp32 output.
__global__ __launch_bounds__(256) void agg16_lsm(const f16* __restrict__ h3,
                                                 const u32* __restrict__ ecol,
                                                 const u32* __restrict__ row_start,
                                                 const float* __restrict__ dinv,
                                                 const float* __restrict__ bias,
                                                 float* __restrict__ out, int M) {
    int g = threadIdx.x >> 4, l = threadIdx.x & 15;
    int r = blockIdx.x * 16 + g;
    if (r >= M) return;
    u32 beg = row_start[r], end = row_start[r + 1];
    float a0 = 0.f, a1 = 0.f, a2 = 0.f, a3 = 0.f;
    u32 e = beg;
    for (; e + 4 <= end; e += 4) {
        u32 c0 = ecol[e], c1 = ecol[e + 1], c2 = ecol[e + 2], c3 = ecol[e + 3];
        a0 += (float)h3[(size_t)c0 * 16 + l];
        a1 += (float)h3[(size_t)c1 * 16 + l];
        a2 += (float)h3[(size_t)c2 * 16 + l];
        a3 += (float)h3[(size_t)c3 * 16 + l];
    }
    for (; e < end; ++e) a0 += (float)h3[(size_t)ecol[e] * 16 + l];
    float dr = dinv[r];
    float acc = (((a0 + a1) + (a2 + a3)) + (float)h3[(size_t)r * 16 + l]) * dr +
                bias[l];
    float m = acc;
#pragma unroll
    for (int o = 8; o >= 1; o >>= 1) m = fmaxf(m, __shfl_xor(m, o, 16));
    float ex = expf(acc - m);
    float s = ex;
#pragma unroll
    for (int o = 8; o >= 1; o >>= 1) s += __shfl_xor(s, o, 16);
    out[(size_t)r * 16 + l] = acc - m - logf(s);
}

// ---------------- launch ----------------

extern "C" void kernel_launch(void* const* d_in, const int* in_sizes, int n_in,
                              void* d_out, int out_size, void* d_ws, size_t ws_size,
                              hipStream_t stream) {
    const float* x = (const float*)d_in[0];
    const int* ei = (const int*)d_in[1];
    const float* W1 = (const float*)d_in[2];
    const float* b1 = (const float*)d_in[3];
    const float* W2 = (const float*)d_in[4];
    const float* b2 = (const float*)d_in[5];
    const float* W3 = (const float*)d_in[6];
    const float* b3 = (const float*)d_in[7];
    int N = in_sizes[0] / D_IN;
    int E = in_sizes[1] / 2;

    char* p = (char*)d_ws;
    auto alloc = [&](size_t bytes) -> void* {
        void* q = (void*)p;
        p += (bytes + 255) & ~(size_t)255;
        return q;
    };
    u32* cnt = (u32*)alloc((size_t)N * 4);
    u32* cursor = (u32*)alloc((size_t)N * 4);
    float* dinv = (float*)alloc((size_t)N * 4);
    u32* row_start = (u32*)alloc((size_t)(N + 1) * 4);
    u32* partial = (u32*)alloc(4096);
    u32* flag = (u32*)alloc(256);
    u32* ecol = (u32*)alloc((size_t)E * 4);
    f16* wf1h = (f16*)alloc(16384 * 2);
    f16* wf1l = (f16*)alloc(16384 * 2);
    f16* wf2h = (f16*)alloc(16384 * 2);
    f16* wf2l = (f16*)alloc(16384 * 2);
    f16* wf3h = (f16*)alloc(2048 * 2);
    f16* wf3l = (f16*)alloc(2048 * 2);
    f16* h = (f16*)alloc((size_t)N * 128 * 2);
    f16* act = (f16*)alloc((size_t)N * 128 * 2);
    f16* h3 = (f16*)alloc((size_t)N * 16 * 2);
    (void)ws_size; (void)n_in; (void)out_size;

    hipMemsetAsync(cnt, 0, (size_t)N * 4, stream);
    hipMemsetAsync(cursor, 0, (size_t)N * 4, stream);
    hipMemsetAsync(flag, 0, 4, stream);

    int eb = (E + 255) / 256;
    int nb = (N + 255) / 256;  // 391 <= 512, scan2 single block handles it
    detect_k<<<32, 256, 0, stream>>>(ei, flag, 8192);
    count_rows<<<eb, 256, 0, stream>>>(ei, flag, cnt, E, N);
    dinv_k<<<nb, 256, 0, stream>>>(cnt, dinv, N);
    scan1<<<nb, 256, 0, stream>>>(cnt, row_start, partial, N);
    scan2<<<1, 512, 0, stream>>>(partial, nb);
    scan3<<<nb, 256, 0, stream>>>(row_start, partial, N, E);

    int W8 = (N + 7) / 8;
    for (int pi = 0; pi < 8; pi++) {
        int lo = pi * W8;
        int hi = lo + W8 < N ? lo + W8 : N;
        scatter_win<<<eb, 256, 0, stream>>>(ei, flag, row_start, cursor, ecol,
                                            E, N, lo, hi);
    }

    reformat_w<<<8, 256, 0, stream>>>(W1, wf1h, wf1l, 8);
    reformat_w<<<8, 256, 0, stream>>>(W2, wf2h, wf2l, 8);
    reformat_w<<<1, 256, 0, stream>>>(W3, wf3h, wf3l, 1);

    int gb = (N + 63) / 64;
    int ab = ((N + 15) / 16) * 4;
    gemm128_l1<<<gb, 256, 0, stream>>>(x, wf1h, wf1l, dinv, h, N);
    agg128_q<<<ab, 256, 0, stream>>>(h, ecol, row_start, dinv, b1, act, N);
    gemm128_l2<<<gb, 256, 0, stream>>>(act, wf2h, wf2l, h, N);
    agg128_q<<<ab, 256, 0, stream>>>(h, ecol, row_start, dinv, b2, act, N);
    gemm16<<<gb, 256, 0, stream>>>(act, wf3h, wf3l, h3, N);
    agg16_lsm<<<(N + 15) / 16, 256, 0, stream>>>(h3, ecol, row_start, dinv, b3,
                                                 (float*)d_out, N);
}

// Round 5
// 517.137 us; speedup vs baseline: 1.1353x; 1.1353x over previous
//
#include <hip/hip_runtime.h>

typedef unsigned int u32;
typedef _Float16 f16;
typedef __attribute__((ext_vector_type(8))) _Float16 half8;
typedef __attribute__((ext_vector_type(2))) _Float16 half2_t;
typedef __attribute__((ext_vector_type(4))) float f32x4;

#define D_IN 128
#define D_HID 128
#define D_OUT 16
#define NBUCK 8

// ---------------- preprocessing ----------------

// flag: 1 if edge_index is int32 layout, 0 if int64 (odd words all zero).
__global__ __launch_bounds__(256) void detect_k(const int* __restrict__ ei,
                                                u32* __restrict__ flag, int n) {
    int i = blockIdx.x * 256 + threadIdx.x;
    if (i < n && (i & 1) && ei[i] != 0) atomicOr(flag, 1u);
}

__device__ inline int load_row(const int* ei, u32 f, int e, int E) {
    return f ? ei[e] : ei[2 * e];
}
__device__ inline int load_col(const int* ei, u32 f, int e, int E) {
    return f ? ei[E + e] : ei[2 * E + 2 * e];
}
__device__ inline int clampi(int v, int n) {
    v = v < 0 ? 0 : v;
    return v >= n ? n - 1 : v;
}

// Phase A: one pass over edges. Degree count + dense append of (r,c) into one
// of 8 row-range buckets (LDS histogram -> one global reserve per bucket per
// block -> coalesced-ish run writes at each bucket frontier).
__global__ __launch_bounds__(256) void bucket_count_k(const int* __restrict__ ei,
                                                      const u32* __restrict__ flag,
                                                      uint2* __restrict__ bdata,
                                                      u32* __restrict__ bcnt,
                                                      u32* __restrict__ cnt,
                                                      int E, int N, int shift, int CAP) {
    __shared__ u32 lcnt[NBUCK];
    __shared__ u32 lbase[NBUCK];
    int tid = threadIdx.x;
    if (tid < NBUCK) lcnt[tid] = 0;
    __syncthreads();
    int e = blockIdx.x * 256 + tid;
    bool valid = e < E;
    int r = 0, c = 0;
    u32 b = 0, rank = 0;
    if (valid) {
        u32 f = *flag;
        r = clampi(load_row(ei, f, e, E), N);
        c = clampi(load_col(ei, f, e, E), N);
        b = (u32)r >> shift;
        rank = atomicAdd(&lcnt[b], 1u);
        atomicAdd(&cnt[r], 1u);
    }
    __syncthreads();
    if (tid < NBUCK) {
        u32 n = lcnt[tid];
        lbase[tid] = n ? atomicAdd(&bcnt[tid], n) : 0u;
    }
    __syncthreads();
    if (valid) {
        u32 pos = lbase[b] + rank;
        if (pos < (u32)CAP) bdata[(size_t)b * CAP + pos] = make_uint2((u32)r, (u32)c);
    }
}

__global__ __launch_bounds__(256) void dinv_k(const u32* __restrict__ cnt,
                                              float* __restrict__ dinv, int n) {
    int i = blockIdx.x * 256 + threadIdx.x;
    if (i < n) dinv[i] = rsqrtf((float)(cnt[i] + 1u));  // +1 self loop
}

__global__ __launch_bounds__(256) void scan1(const u32* __restrict__ cnt,
                                             u32* __restrict__ excl,
                                             u32* __restrict__ partial, int n) {
    __shared__ u32 sm[256];
    int tid = threadIdx.x;
    int i = blockIdx.x * 256 + tid;
    u32 v = (i < n) ? cnt[i] : 0u;
    sm[tid] = v;
    __syncthreads();
    for (int off = 1; off < 256; off <<= 1) {
        u32 t = (tid >= off) ? sm[tid - off] : 0u;
        __syncthreads();
        sm[tid] += t;
        __syncthreads();
    }
    if (i < n) excl[i] = sm[tid] - v;
    if (tid == 255) partial[blockIdx.x] = sm[255];
}

__global__ __launch_bounds__(512) void scan2(u32* __restrict__ partial, int nb) {
    __shared__ u32 sm[512];
    int tid = threadIdx.x;
    u32 v = (tid < nb) ? partial[tid] : 0u;
    sm[tid] = v;
    __syncthreads();
    for (int off = 1; off < 512; off <<= 1) {
        u32 t = (tid >= off) ? sm[tid - off] : 0u;
        __syncthreads();
        sm[tid] += t;
        __syncthreads();
    }
    if (tid < nb) partial[tid] = sm[tid] - v;
}

__global__ __launch_bounds__(256) void scan3(u32* __restrict__ excl,
                                             const u32* __restrict__ partial,
                                             int n, int E) {
    int i = blockIdx.x * 256 + threadIdx.x;
    if (i < n) excl[i] += partial[blockIdx.x];
    if (i == 0) excl[n] = (u32)E;
}

// Phase B: per bucket (blockIdx.y), sequential read of dense (r,c) records,
// scatter col into the bucket's ~1MB L2-resident ecol window.
__global__ __launch_bounds__(256) void unbucket_k(const uint2* __restrict__ bdata,
                                                  const u32* __restrict__ bcnt,
                                                  const u32* __restrict__ row_start,
                                                  u32* __restrict__ cursor,
                                                  u32* __restrict__ ecol,
                                                  int E, int CAP) {
    int b = blockIdx.y;
    u32 n = bcnt[b];
    if (n > (u32)CAP) n = (u32)CAP;
    const uint2* bd = bdata + (size_t)b * CAP;
    for (u32 i = blockIdx.x * 256 + threadIdx.x; i < n; i += gridDim.x * 256) {
        uint2 rc = bd[i];
        u32 pos = row_start[rc.x] + atomicAdd(&cursor[rc.x], 1u);
        if (pos < (u32)E) ecol[pos] = rc.y;
    }
}

// Split fp32 W [128 x (ntiles*16)] into hi/lo f16 MFMA B-fragments.
__global__ __launch_bounds__(256) void reformat_w(const float* __restrict__ W,
                                                  f16* __restrict__ Wh,
                                                  f16* __restrict__ Wl, int ntiles) {
    int idx = blockIdx.x * 256 + threadIdx.x;
    int total = 4 * ntiles * 64;
    if (idx >= total) return;
    int lane = idx & 63;
    int st = idx >> 6;
    int t = st % ntiles;
    int s = st / ntiles;
    int Nc = ntiles * 16;
    int n = t * 16 + (lane & 15);
    int kb = lane >> 4;
    half8 vh, vl;
#pragma unroll
    for (int j = 0; j < 8; j++) {
        float w = W[(size_t)(s * 32 + kb * 8 + j) * Nc + n];
        f16 hi = (f16)w;
        f16 lo = (f16)(w - (float)hi);
        vh[j] = hi;
        vl[j] = lo;
    }
    *(half8*)(Wh + (size_t)idx * 8) = vh;
    *(half8*)(Wl + (size_t)idx * 8) = vl;
}

// ---------------- GEMMs (f16 MFMA 16x16x32, fp32-accurate via splits) --------

// Layer 1: A fp32 [M x 128]; 3 MFMAs; epilogue scales row rr by dinv[rr]
// so the stored table is h' = (x@W1)*dinv  (norm folded into storage).
__global__ __launch_bounds__(256) void gemm128_l1(const float* __restrict__ A,
                                                  const f16* __restrict__ Wh,
                                                  const f16* __restrict__ Wl,
                                                  const float* __restrict__ dinv,
                                                  f16* __restrict__ H, int M) {
    int wave = threadIdx.x >> 6, lane = threadIdx.x & 63;
    int mbase = blockIdx.x * 64 + wave * 16;
    int mload = mbase + (lane & 15);
    if (mload >= M) mload = M - 1;
    int kq = lane >> 4;
    f32x4 acc[8];
#pragma unroll
    for (int t = 0; t < 8; t++) acc[t] = (f32x4){0.f, 0.f, 0.f, 0.f};
#pragma unroll
    for (int s = 0; s < 4; s++) {
        const float* ap = A + (size_t)mload * 128 + s * 32 + kq * 8;
        half8 ah, al;
#pragma unroll
        for (int j = 0; j < 8; j++) {
            float v = ap[j];
            f16 hi = (f16)v;
            ah[j] = hi;
            al[j] = (f16)(v - (float)hi);
        }
#pragma unroll
        for (int t = 0; t < 8; t++) {
            half8 bh = *(const half8*)(Wh + (size_t)((s * 8 + t) * 64 + lane) * 8);
            half8 bl = *(const half8*)(Wl + (size_t)((s * 8 + t) * 64 + lane) * 8);
            acc[t] = __builtin_amdgcn_mfma_f32_16x16x32_f16(ah, bh, acc[t], 0, 0, 0);
            acc[t] = __builtin_amdgcn_mfma_f32_16x16x32_f16(ah, bl, acc[t], 0, 0, 0);
            acc[t] = __builtin_amdgcn_mfma_f32_16x16x32_f16(al, bh, acc[t], 0, 0, 0);
        }
    }
    int coln = lane & 15;
    int rbase = mbase + ((lane >> 4) << 2);
    float dsc[4];
#pragma unroll
    for (int i = 0; i < 4; i++) {
        int rr = rbase + i;
        dsc[i] = dinv[rr < M ? rr : M - 1];
    }
#pragma unroll
    for (int t = 0; t < 8; t++) {
#pragma unroll
        for (int i = 0; i < 4; i++) {
            int rr = rbase + i;
            if (rr < M) H[(size_t)rr * 128 + t * 16 + coln] = (f16)(acc[t][i] * dsc[i]);
        }
    }
}

// Layer 2: A f16 (pre-scaled act') [M x 128]; 2 MFMAs; output inherits the
// dinv row-scale automatically ((act*dinv)@W = (act@W)*dinv).
__global__ __launch_bounds__(256) void gemm128_l2(const f16* __restrict__ A,
                                                  const f16* __restrict__ Wh,
                                                  const f16* __restrict__ Wl,
                                                  f16* __restrict__ H, int M) {
    int wave = threadIdx.x >> 6, lane = threadIdx.x & 63;
    int mbase = blockIdx.x * 64 + wave * 16;
    int mload = mbase + (lane & 15);
    if (mload >= M) mload = M - 1;
    int kq = lane >> 4;
    f32x4 acc[8];
#pragma unroll
    for (int t = 0; t < 8; t++) acc[t] = (f32x4){0.f, 0.f, 0.f, 0.f};
#pragma unroll
    for (int s = 0; s < 4; s++) {
        half8 a = *(const half8*)(A + (size_t)mload * 128 + s * 32 + kq * 8);
#pragma unroll
        for (int t = 0; t < 8; t++) {
            half8 bh = *(const half8*)(Wh + (size_t)((s * 8 + t) * 64 + lane) * 8);
            half8 bl = *(const half8*)(Wl + (size_t)((s * 8 + t) * 64 + lane) * 8);
            acc[t] = __builtin_amdgcn_mfma_f32_16x16x32_f16(a, bh, acc[t], 0, 0, 0);
            acc[t] = __builtin_amdgcn_mfma_f32_16x16x32_f16(a, bl, acc[t], 0, 0, 0);
        }
    }
    int coln = lane & 15;
    int rbase = mbase + ((lane >> 4) << 2);
#pragma unroll
    for (int t = 0; t < 8; t++) {
#pragma unroll
        for (int i = 0; i < 4; i++) {
            int rr = rbase + i;
            if (rr < M) H[(size_t)rr * 128 + t * 16 + coln] = (f16)acc[t][i];
        }
    }
}

// Layer 3: A f16 (pre-scaled) [M x 128] -> H3' f16 [M x 16].
__global__ __launch_bounds__(256) void gemm16(const f16* __restrict__ A,
                                              const f16* __restrict__ Wh,
                                              const f16* __restrict__ Wl,
                                              f16* __restrict__ H, int M) {
    int wave = threadIdx.x >> 6, lane = threadIdx.x & 63;
    int mbase = blockIdx.x * 64 + wave * 16;
    int mload = mbase + (lane & 15);
    if (mload >= M) mload = M - 1;
    int kq = lane >> 4;
    f32x4 acc = (f32x4){0.f, 0.f, 0.f, 0.f};
#pragma unroll
    for (int s = 0; s < 4; s++) {
        half8 a = *(const half8*)(A + (size_t)mload * 128 + s * 32 + kq * 8);
        half8 bh = *(const half8*)(Wh + (size_t)(s * 64 + lane) * 8);
        half8 bl = *(const half8*)(Wl + (size_t)(s * 64 + lane) * 8);
        acc = __builtin_amdgcn_mfma_f32_16x16x32_f16(a, bh, acc, 0, 0, 0);
        acc = __builtin_amdgcn_mfma_f32_16x16x32_f16(a, bl, acc, 0, 0, 0);
    }
    int coln = lane & 15;
    int rbase = mbase + ((lane >> 4) << 2);
#pragma unroll
    for (int i = 0; i < 4; i++) {
        int rr = rbase + i;
        if (rr < M) H[(size_t)rr * 16 + coln] = (f16)acc[i];
    }
}

// ---------------- aggregation ----------------
// One wave per row; lane handles features 2*lane, 2*lane+1 (half2, 4B/lane ->
// one coalesced 256B gather per edge). Unroll 16 for MLP.
// out = relu(dinv[r]*(sum h'[c] + h'[r]) + b) * dinv[r]   (h' pre-scaled).
__global__ __launch_bounds__(256) void agg128(const f16* __restrict__ h,
                                              const u32* __restrict__ ecol,
                                              const u32* __restrict__ row_start,
                                              const float* __restrict__ dinv,
                                              const float* __restrict__ bias,
                                              f16* __restrict__ out, int M) {
    int wave = threadIdx.x >> 6, lane = threadIdx.x & 63;
    int r = blockIdx.x * 4 + wave;
    if (r >= M) return;
    u32 beg = row_start[r], end = row_start[r + 1];
    const half2_t* hp = (const half2_t*)h;
    float ax0 = 0, ay0 = 0, ax1 = 0, ay1 = 0, ax2 = 0, ay2 = 0, ax3 = 0, ay3 = 0;
    u32 e = beg;
    for (; e + 16 <= end; e += 16) {
        u32 c[16];
#pragma unroll
        for (int j = 0; j < 16; j++) c[j] = ecol[e + j];
        half2_t v[16];
#pragma unroll
        for (int j = 0; j < 16; j++) v[j] = hp[(size_t)c[j] * 64 + lane];
#pragma unroll
        for (int j = 0; j < 16; j += 4) {
            ax0 += (float)v[j][0];     ay0 += (float)v[j][1];
            ax1 += (float)v[j + 1][0]; ay1 += (float)v[j + 1][1];
            ax2 += (float)v[j + 2][0]; ay2 += (float)v[j + 2][1];
            ax3 += (float)v[j + 3][0]; ay3 += (float)v[j + 3][1];
        }
    }
    for (; e + 4 <= end; e += 4) {
        u32 c0 = ecol[e], c1 = ecol[e + 1], c2 = ecol[e + 2], c3 = ecol[e + 3];
        half2_t v0 = hp[(size_t)c0 * 64 + lane];
        half2_t v1 = hp[(size_t)c1 * 64 + lane];
        half2_t v2 = hp[(size_t)c2 * 64 + lane];
        half2_t v3 = hp[(size_t)c3 * 64 + lane];
        ax0 += (float)v0[0]; ay0 += (float)v0[1];
        ax1 += (float)v1[0]; ay1 += (float)v1[1];
        ax2 += (float)v2[0]; ay2 += (float)v2[1];
        ax3 += (float)v3[0]; ay3 += (float)v3[1];
    }
    for (; e < end; ++e) {
        half2_t v = hp[(size_t)ecol[e] * 64 + lane];
        ax0 += (float)v[0]; ay0 += (float)v[1];
    }
    half2_t vs = hp[(size_t)r * 64 + lane];
    float dr = dinv[r];
    float2 bb = ((const float2*)bias)[lane];
    float ax = (((ax0 + ax1) + (ax2 + ax3)) + (float)vs[0]) * dr + bb.x;
    float ay = (((ay0 + ay1) + (ay2 + ay3)) + (float)vs[1]) * dr + bb.y;
    ax = fmaxf(ax, 0.f) * dr;  // pre-scale for next layer's gather
    ay = fmaxf(ay, 0.f) * dr;
    half2_t o;
    o[0] = (f16)ax;
    o[1] = (f16)ay;
    ((half2_t*)out)[(size_t)r * 64 + lane] = o;
}

// 16 lanes per row; h3' pre-scaled; fused bias + log_softmax; fp32 output.
__global__ __launch_bounds__(256) void agg16_lsm(const f16* __restrict__ h3,
                                                 const u32* __restrict__ ecol,
                                                 const u32* __restrict__ row_start,
                                                 const float* __restrict__ dinv,
                                                 const float* __restrict__ bias,
                                                 float* __restrict__ out, int M) {
    int g = threadIdx.x >> 4, l = threadIdx.x & 15;
    int r = blockIdx.x * 16 + g;
    if (r >= M) return;
    u32 beg = row_start[r], end = row_start[r + 1];
    float a0 = 0.f, a1 = 0.f, a2 = 0.f, a3 = 0.f;
    u32 e = beg;
    for (; e + 4 <= end; e += 4) {
        u32 c0 = ecol[e], c1 = ecol[e + 1], c2 = ecol[e + 2], c3 = ecol[e + 3];
        a0 += (float)h3[(size_t)c0 * 16 + l];
        a1 += (float)h3[(size_t)c1 * 16 + l];
        a2 += (float)h3[(size_t)c2 * 16 + l];
        a3 += (float)h3[(size_t)c3 * 16 + l];
    }
    for (; e < end; ++e) a0 += (float)h3[(size_t)ecol[e] * 16 + l];
    float dr = dinv[r];
    float acc = (((a0 + a1) + (a2 + a3)) + (float)h3[(size_t)r * 16 + l]) * dr +
                bias[l];
    float m = acc;
#pragma unroll
    for (int o = 8; o >= 1; o >>= 1) m = fmaxf(m, __shfl_xor(m, o, 16));
    float ex = expf(acc - m);
    float s = ex;
#pragma unroll
    for (int o = 8; o >= 1; o >>= 1) s += __shfl_xor(s, o, 16);
    out[(size_t)r * 16 + l] = acc - m - logf(s);
}

// ---------------- launch ----------------

extern "C" void kernel_launch(void* const* d_in, const int* in_sizes, int n_in,
                              void* d_out, int out_size, void* d_ws, size_t ws_size,
                              hipStream_t stream) {
    const float* x = (const float*)d_in[0];
    const int* ei = (const int*)d_in[1];
    const float* W1 = (const float*)d_in[2];
    const float* b1 = (const float*)d_in[3];
    const float* W2 = (const float*)d_in[4];
    const float* b2 = (const float*)d_in[5];
    const float* W3 = (const float*)d_in[6];
    const float* b3 = (const float*)d_in[7];
    int N = in_sizes[0] / D_IN;
    int E = in_sizes[1] / 2;

    // bucket shift: rows >> shift must fit in NBUCK buckets
    int shift = 0;
    while (((N - 1) >> shift) >= NBUCK) shift++;
    int CAP = E / 4 + 1024;

    char* p = (char*)d_ws;
    auto alloc = [&](size_t bytes) -> void* {
        void* q = (void*)p;
        p += (bytes + 255) & ~(size_t)255;
        return q;
    };
    u32* cnt = (u32*)alloc((size_t)N * 4);
    u32* cursor = (u32*)alloc((size_t)N * 4);
    float* dinv = (float*)alloc((size_t)N * 4);
    u32* row_start = (u32*)alloc((size_t)(N + 1) * 4);
    u32* partial = (u32*)alloc(4096);
    u32* flag = (u32*)alloc(256);
    u32* bcnt = (u32*)alloc(256);
    u32* ecol = (u32*)alloc((size_t)E * 4);
    uint2* bdata = (uint2*)alloc((size_t)NBUCK * CAP * 8);
    f16* wf1h = (f16*)alloc(16384 * 2);
    f16* wf1l = (f16*)alloc(16384 * 2);
    f16* wf2h = (f16*)alloc(16384 * 2);
    f16* wf2l = (f16*)alloc(16384 * 2);
    f16* wf3h = (f16*)alloc(2048 * 2);
    f16* wf3l = (f16*)alloc(2048 * 2);
    f16* h = (f16*)alloc((size_t)N * 128 * 2);
    f16* act = (f16*)alloc((size_t)N * 128 * 2);
    f16* h3 = (f16*)alloc((size_t)N * 16 * 2);
    (void)ws_size; (void)n_in; (void)out_size;

    hipMemsetAsync(cnt, 0, (size_t)N * 4, stream);
    hipMemsetAsync(cursor, 0, (size_t)N * 4, stream);
    hipMemsetAsync(flag, 0, 4, stream);
    hipMemsetAsync(bcnt, 0, 256, stream);

    int eb = (E + 255) / 256;
    int nb = (N + 255) / 256;  // 391 <= 512, scan2 single block handles it
    detect_k<<<32, 256, 0, stream>>>(ei, flag, 8192);
    bucket_count_k<<<eb, 256, 0, stream>>>(ei, flag, bdata, bcnt, cnt, E, N,
                                           shift, CAP);
    dinv_k<<<nb, 256, 0, stream>>>(cnt, dinv, N);
    scan1<<<nb, 256, 0, stream>>>(cnt, row_start, partial, N);
    scan2<<<1, 512, 0, stream>>>(partial, nb);
    scan3<<<nb, 256, 0, stream>>>(row_start, partial, N, E);
    unbucket_k<<<dim3(512, NBUCK), 256, 0, stream>>>(bdata, bcnt, row_start,
                                                     cursor, ecol, E, CAP);

    reformat_w<<<8, 256, 0, stream>>>(W1, wf1h, wf1l, 8);
    reformat_w<<<8, 256, 0, stream>>>(W2, wf2h, wf2l, 8);
    reformat_w<<<1, 256, 0, stream>>>(W3, wf3h, wf3l, 1);

    int gb = (N + 63) / 64;
    int ab = (N + 3) / 4;
    gemm128_l1<<<gb, 256, 0, stream>>>(x, wf1h, wf1l, dinv, h, N);
    agg128<<<ab, 256, 0, stream>>>(h, ecol, row_start, dinv, b1, act, N);
    gemm128_l2<<<gb, 256, 0, stream>>>(act, wf2h, wf2l, h, N);
    agg128<<<ab, 256, 0, stream>>>(h, ecol, row_start, dinv, b2, act, N);
    gemm16<<<gb, 256, 0, stream>>>(act, wf3h, wf3l, h3, N);
    agg16_lsm<<<(N + 15) / 16, 256, 0, stream>>>(h3, ecol, row_start, dinv, b3,
                                                 (float*)d_out, N);
}

// Round 6
// 491.661 us; speedup vs baseline: 1.1941x; 1.0518x over previous
//
#include <hip/hip_runtime.h>

typedef unsigned int u32;
typedef _Float16 f16;
typedef __attribute__((ext_vector_type(8))) _Float16 half8;
typedef __attribute__((ext_vector_type(2))) _Float16 half2_t;
typedef __attribute__((ext_vector_type(4))) float f32x4;

#define D_IN 128
#define D_HID 128
#define D_OUT 16
#define NBUCK 8
#define CHUNK 2048  // edges per hist/scatter block (256 thr x 8)

// ---------------- preprocessing ----------------

// flag: 1 if edge_index is int32 layout, 0 if int64 (odd words all zero).
__global__ __launch_bounds__(256) void detect_k(const int* __restrict__ ei,
                                                u32* __restrict__ flag, int n) {
    int i = blockIdx.x * 256 + threadIdx.x;
    if (i < n && (i & 1) && ei[i] != 0) atomicOr(flag, 1u);
}

__device__ inline int load_row(const int* ei, u32 f, int e, int E) {
    return f ? ei[e] : ei[2 * e];
}
__device__ inline int load_col(const int* ei, u32 f, int e, int E) {
    return f ? ei[E + e] : ei[2 * E + 2 * e];
}
__device__ inline int clampi(int v, int n) {
    v = v < 0 ? 0 : v;
    return v >= n ? n - 1 : v;
}

// Per-block bucket histogram (bucket-major matrix, plain stores — no global
// return-atomics) + fire-and-forget degree count.
__global__ __launch_bounds__(256) void hist_k(const int* __restrict__ ei,
                                              const u32* __restrict__ flag,
                                              u32* __restrict__ Hmat,
                                              u32* __restrict__ cnt,
                                              int E, int N, int shift, int NB) {
    __shared__ u32 lh[NBUCK];
    int tid = threadIdx.x;
    if (tid < NBUCK) lh[tid] = 0;
    __syncthreads();
    u32 f = *flag;
    int base = blockIdx.x * CHUNK;
#pragma unroll
    for (int j = 0; j < CHUNK / 256; j++) {
        int e = base + j * 256 + tid;
        if (e < E) {
            int r = clampi(load_row(ei, f, e, E), N);
            atomicAdd(&lh[(u32)r >> shift], 1u);
            atomicAdd(&cnt[r], 1u);
        }
    }
    __syncthreads();
    if (tid < NBUCK) Hmat[(size_t)tid * NB + blockIdx.x] = lh[tid];
}

__global__ __launch_bounds__(256) void scan1(const u32* __restrict__ cnt,
                                             u32* __restrict__ excl,
                                             u32* __restrict__ partial, int n) {
    __shared__ u32 sm[256];
    int tid = threadIdx.x;
    int i = blockIdx.x * 256 + tid;
    u32 v = (i < n) ? cnt[i] : 0u;
    sm[tid] = v;
    __syncthreads();
    for (int off = 1; off < 256; off <<= 1) {
        u32 t = (tid >= off) ? sm[tid - off] : 0u;
        __syncthreads();
        sm[tid] += t;
        __syncthreads();
    }
    if (i < n) excl[i] = sm[tid] - v;
    if (tid == 255) partial[blockIdx.x] = sm[255];
}

// scan1 variant that also emits dinv = rsqrt(deg+1) (fuses old dinv_k).
__global__ __launch_bounds__(256) void scan1_dinv(const u32* __restrict__ cnt,
                                                  u32* __restrict__ excl,
                                                  u32* __restrict__ partial,
                                                  float* __restrict__ dinv, int n) {
    __shared__ u32 sm[256];
    int tid = threadIdx.x;
    int i = blockIdx.x * 256 + tid;
    u32 v = (i < n) ? cnt[i] : 0u;
    if (i < n) dinv[i] = rsqrtf((float)(v + 1u));  // +1 self loop
    sm[tid] = v;
    __syncthreads();
    for (int off = 1; off < 256; off <<= 1) {
        u32 t = (tid >= off) ? sm[tid - off] : 0u;
        __syncthreads();
        sm[tid] += t;
        __syncthreads();
    }
    if (i < n) excl[i] = sm[tid] - v;
    if (tid == 255) partial[blockIdx.x] = sm[255];
}

__global__ __launch_bounds__(512) void scan2(u32* __restrict__ partial, int nb) {
    __shared__ u32 sm[512];
    int tid = threadIdx.x;
    u32 v = (tid < nb) ? partial[tid] : 0u;
    sm[tid] = v;
    __syncthreads();
    for (int off = 1; off < 512; off <<= 1) {
        u32 t = (tid >= off) ? sm[tid - off] : 0u;
        __syncthreads();
        sm[tid] += t;
        __syncthreads();
    }
    if (tid < nb) partial[tid] = sm[tid] - v;
}

__global__ __launch_bounds__(256) void scan3(u32* __restrict__ excl,
                                             const u32* __restrict__ partial,
                                             int n, int E) {
    int i = blockIdx.x * 256 + threadIdx.x;
    if (i < n) excl[i] += partial[blockIdx.x];
    if (i == 0) excl[n] = (u32)E;
}

// Re-read edges; each block's run positions are exact (Hbase), so only
// block-local LDS atomics are needed. Writes dense (r,c) records, bucket-major.
__global__ __launch_bounds__(256) void scatter_bd(const int* __restrict__ ei,
                                                  const u32* __restrict__ flag,
                                                  const u32* __restrict__ Hbase,
                                                  uint2* __restrict__ bdata,
                                                  int E, int N, int shift, int NB) {
    __shared__ u32 lbase[NBUCK];
    int tid = threadIdx.x;
    if (tid < NBUCK) lbase[tid] = Hbase[(size_t)tid * NB + blockIdx.x];
    __syncthreads();
    u32 f = *flag;
    int base = blockIdx.x * CHUNK;
#pragma unroll
    for (int j = 0; j < CHUNK / 256; j++) {
        int e = base + j * 256 + tid;
        if (e < E) {
            int r = clampi(load_row(ei, f, e, E), N);
            int c = clampi(load_col(ei, f, e, E), N);
            u32 pos = atomicAdd(&lbase[(u32)r >> shift], 1u);
            if (pos < (u32)E) bdata[pos] = make_uint2((u32)r, (u32)c);
        }
    }
}

// Per bucket (blockIdx.y): sequential read of dense (r,c), scatter col into the
// bucket's ~800KB L2-resident ecol window via per-row cursors.
__global__ __launch_bounds__(256) void unbucket_k(const uint2* __restrict__ bdata,
                                                  const u32* __restrict__ Hbase,
                                                  const u32* __restrict__ row_start,
                                                  u32* __restrict__ cursor,
                                                  u32* __restrict__ ecol,
                                                  int E, int NB) {
    int b = blockIdx.y;
    u32 s = Hbase[(size_t)b * NB];
    u32 t = Hbase[(size_t)(b + 1) * NB];  // b=7 hits sentinel Hbase[8*NB]=E
    for (u32 i = s + blockIdx.x * 256 + threadIdx.x; i < t; i += gridDim.x * 256) {
        uint2 rc = bdata[i];
        u32 pos = row_start[rc.x] + atomicAdd(&cursor[rc.x], 1u);
        if (pos < (u32)E) ecol[pos] = rc.y;
    }
}

// Split fp32 W into hi/lo f16 MFMA B-fragments. One dispatch covers all three
// weight matrices: blocks 0-7 -> W1, 8-15 -> W2, 16 -> W3.
__global__ __launch_bounds__(256) void reformat_all(const float* __restrict__ W1,
                                                    const float* __restrict__ W2,
                                                    const float* __restrict__ W3,
                                                    f16* __restrict__ W1h, f16* __restrict__ W1l,
                                                    f16* __restrict__ W2h, f16* __restrict__ W2l,
                                                    f16* __restrict__ W3h, f16* __restrict__ W3l) {
    const float* W;
    f16 *Wh, *Wl;
    int ntiles, bidx;
    if (blockIdx.x < 8) { W = W1; Wh = W1h; Wl = W1l; ntiles = 8; bidx = blockIdx.x; }
    else if (blockIdx.x < 16) { W = W2; Wh = W2h; Wl = W2l; ntiles = 8; bidx = blockIdx.x - 8; }
    else { W = W3; Wh = W3h; Wl = W3l; ntiles = 1; bidx = 0; }
    int idx = bidx * 256 + threadIdx.x;
    int total = 4 * ntiles * 64;
    if (idx >= total) return;
    int lane = idx & 63;
    int st = idx >> 6;
    int t = st % ntiles;
    int s = st / ntiles;
    int Nc = ntiles * 16;
    int n = t * 16 + (lane & 15);
    int kb = lane >> 4;
    half8 vh, vl;
#pragma unroll
    for (int j = 0; j < 8; j++) {
        float w = W[(size_t)(s * 32 + kb * 8 + j) * Nc + n];
        f16 hi = (f16)w;
        f16 lo = (f16)(w - (float)hi);
        vh[j] = hi;
        vl[j] = lo;
    }
    *(half8*)(Wh + (size_t)idx * 8) = vh;
    *(half8*)(Wl + (size_t)idx * 8) = vl;
}

// ---------------- GEMMs (f16 MFMA 16x16x32, fp32-accurate via splits) --------

// Layer 1: A fp32 [M x 128]; 3 MFMAs; epilogue scales row rr by dinv[rr]
// so the stored table is h' = (x@W1)*dinv  (norm folded into storage).
__global__ __launch_bounds__(256) void gemm128_l1(const float* __restrict__ A,
                                                  const f16* __restrict__ Wh,
                                                  const f16* __restrict__ Wl,
                                                  const float* __restrict__ dinv,
                                                  f16* __restrict__ H, int M) {
    int wave = threadIdx.x >> 6, lane = threadIdx.x & 63;
    int mbase = blockIdx.x * 64 + wave * 16;
    int mload = mbase + (lane & 15);
    if (mload >= M) mload = M - 1;
    int kq = lane >> 4;
    f32x4 acc[8];
#pragma unroll
    for (int t = 0; t < 8; t++) acc[t] = (f32x4){0.f, 0.f, 0.f, 0.f};
#pragma unroll
    for (int s = 0; s < 4; s++) {
        const float* ap = A + (size_t)mload * 128 + s * 32 + kq * 8;
        half8 ah, al;
#pragma unroll
        for (int j = 0; j < 8; j++) {
            float v = ap[j];
            f16 hi = (f16)v;
            ah[j] = hi;
            al[j] = (f16)(v - (float)hi);
        }
#pragma unroll
        for (int t = 0; t < 8; t++) {
            half8 bh = *(const half8*)(Wh + (size_t)((s * 8 + t) * 64 + lane) * 8);
            half8 bl = *(const half8*)(Wl + (size_t)((s * 8 + t) * 64 + lane) * 8);
            acc[t] = __builtin_amdgcn_mfma_f32_16x16x32_f16(ah, bh, acc[t], 0, 0, 0);
            acc[t] = __builtin_amdgcn_mfma_f32_16x16x32_f16(ah, bl, acc[t], 0, 0, 0);
            acc[t] = __builtin_amdgcn_mfma_f32_16x16x32_f16(al, bh, acc[t], 0, 0, 0);
        }
    }
    int coln = lane & 15;
    int rbase = mbase + ((lane >> 4) << 2);
    float dsc[4];
#pragma unroll
    for (int i = 0; i < 4; i++) {
        int rr = rbase + i;
        dsc[i] = dinv[rr < M ? rr : M - 1];
    }
#pragma unroll
    for (int t = 0; t < 8; t++) {
#pragma unroll
        for (int i = 0; i < 4; i++) {
            int rr = rbase + i;
            if (rr < M) H[(size_t)rr * 128 + t * 16 + coln] = (f16)(acc[t][i] * dsc[i]);
        }
    }
}

// Layer 2: A f16 (pre-scaled act') [M x 128]; 2 MFMAs; output inherits the
// dinv row-scale automatically ((act*dinv)@W = (act@W)*dinv).
__global__ __launch_bounds__(256) void gemm128_l2(const f16* __restrict__ A,
                                                  const f16* __restrict__ Wh,
                                                  const f16* __restrict__ Wl,
                                                  f16* __restrict__ H, int M) {
    int wave = threadIdx.x >> 6, lane = threadIdx.x & 63;
    int mbase = blockIdx.x * 64 + wave * 16;
    int mload = mbase + (lane & 15);
    if (mload >= M) mload = M - 1;
    int kq = lane >> 4;
    f32x4 acc[8];
#pragma unroll
    for (int t = 0; t < 8; t++) acc[t] = (f32x4){0.f, 0.f, 0.f, 0.f};
#pragma unroll
    for (int s = 0; s < 4; s++) {
        half8 a = *(const half8*)(A + (size_t)mload * 128 + s * 32 + kq * 8);
#pragma unroll
        for (int t = 0; t < 8; t++) {
            half8 bh = *(const half8*)(Wh + (size_t)((s * 8 + t) * 64 + lane) * 8);
            half8 bl = *(const half8*)(Wl + (size_t)((s * 8 + t) * 64 + lane) * 8);
            acc[t] = __builtin_amdgcn_mfma_f32_16x16x32_f16(a, bh, acc[t], 0, 0, 0);
            acc[t] = __builtin_amdgcn_mfma_f32_16x16x32_f16(a, bl, acc[t], 0, 0, 0);
        }
    }
    int coln = lane & 15;
    int rbase = mbase + ((lane >> 4) << 2);
#pragma unroll
    for (int t = 0; t < 8; t++) {
#pragma unroll
        for (int i = 0; i < 4; i++) {
            int rr = rbase + i;
            if (rr < M) H[(size_t)rr * 128 + t * 16 + coln] = (f16)acc[t][i];
        }
    }
}

// Layer 3: A f16 (pre-scaled) [M x 128] -> H3' f16 [M x 16].
__global__ __launch_bounds__(256) void gemm16(const f16* __restrict__ A,
                                              const f16* __restrict__ Wh,
                                              const f16* __restrict__ Wl,
                                              f16* __restrict__ H, int M) {
    int wave = threadIdx.x >> 6, lane = threadIdx.x & 63;
    int mbase = blockIdx.x * 64 + wave * 16;
    int mload = mbase + (lane & 15);
    if (mload >= M) mload = M - 1;
    int kq = lane >> 4;
    f32x4 acc = (f32x4){0.f, 0.f, 0.f, 0.f};
#pragma unroll
    for (int s = 0; s < 4; s++) {
        half8 a = *(const half8*)(A + (size_t)mload * 128 + s * 32 + kq * 8);
        half8 bh = *(const half8*)(Wh + (size_t)(s * 64 + lane) * 8);
        half8 bl = *(const half8*)(Wl + (size_t)(s * 64 + lane) * 8);
        acc = __builtin_amdgcn_mfma_f32_16x16x32_f16(a, bh, acc, 0, 0, 0);
        acc = __builtin_amdgcn_mfma_f32_16x16x32_f16(a, bl, acc, 0, 0, 0);
    }
    int coln = lane & 15;
    int rbase = mbase + ((lane >> 4) << 2);
#pragma unroll
    for (int i = 0; i < 4; i++) {
        int rr = rbase + i;
        if (rr < M) H[(size_t)rr * 16 + coln] = (f16)acc[i];
    }
}

// ---------------- aggregation ----------------
// One wave per row; lane handles features 2*lane, 2*lane+1 (half2, 4B/lane ->
// one coalesced 256B gather per edge). Unroll 16 for MLP.
// out = relu(dinv[r]*(sum h'[c] + h'[r]) + b) * dinv[r]   (h' pre-scaled).
__global__ __launch_bounds__(256) void agg128(const f16* __restrict__ h,
                                              const u32* __restrict__ ecol,
                                              const u32* __restrict__ row_start,
                                              const float* __restrict__ dinv,
                                              const float* __restrict__ bias,
                                              f16* __restrict__ out, int M) {
    int wave = threadIdx.x >> 6, lane = threadIdx.x & 63;
    int r = blockIdx.x * 4 + wave;
    if (r >= M) return;
    u32 beg = row_start[r], end = row_start[r + 1];
    const half2_t* hp = (const half2_t*)h;
    float ax0 = 0, ay0 = 0, ax1 = 0, ay1 = 0, ax2 = 0, ay2 = 0, ax3 = 0, ay3 = 0;
    u32 e = beg;
    for (; e + 16 <= end; e += 16) {
        u32 c[16];
#pragma unroll
        for (int j = 0; j < 16; j++) c[j] = ecol[e + j];
        half2_t v[16];
#pragma unroll
        for (int j = 0; j < 16; j++) v[j] = hp[(size_t)c[j] * 64 + lane];
#pragma unroll
        for (int j = 0; j < 16; j += 4) {
            ax0 += (float)v[j][0];     ay0 += (float)v[j][1];
            ax1 += (float)v[j + 1][0]; ay1 += (float)v[j + 1][1];
            ax2 += (float)v[j + 2][0]; ay2 += (float)v[j + 2][1];
            ax3 += (float)v[j + 3][0]; ay3 += (float)v[j + 3][1];
        }
    }
    for (; e + 4 <= end; e += 4) {
        u32 c0 = ecol[e], c1 = ecol[e + 1], c2 = ecol[e + 2], c3 = ecol[e + 3];
        half2_t v0 = hp[(size_t)c0 * 64 + lane];
        half2_t v1 = hp[(size_t)c1 * 64 + lane];
        half2_t v2 = hp[(size_t)c2 * 64 + lane];
        half2_t v3 = hp[(size_t)c3 * 64 + lane];
        ax0 += (float)v0[0]; ay0 += (float)v0[1];
        ax1 += (float)v1[0]; ay1 += (float)v1[1];
        ax2 += (float)v2[0]; ay2 += (float)v2[1];
        ax3 += (float)v3[0]; ay3 += (float)v3[1];
    }
    for (; e < end; ++e) {
        half2_t v = hp[(size_t)ecol[e] * 64 + lane];
        ax0 += (float)v[0]; ay0 += (float)v[1];
    }
    half2_t vs = hp[(size_t)r * 64 + lane];
    float dr = dinv[r];
    float2 bb = ((const float2*)bias)[lane];
    float ax = (((ax0 + ax1) + (ax2 + ax3)) + (float)vs[0]) * dr + bb.x;
    float ay = (((ay0 + ay1) + (ay2 + ay3)) + (float)vs[1]) * dr + bb.y;
    ax = fmaxf(ax, 0.f) * dr;  // pre-scale for next layer's gather
    ay = fmaxf(ay, 0.f) * dr;
    half2_t o;
    o[0] = (f16)ax;
    o[1] = (f16)ay;
    ((half2_t*)out)[(size_t)r * 64 + lane] = o;
}

// 16 lanes per row; h3' pre-scaled; fused bias + log_softmax; fp32 output.
__global__ __launch_bounds__(256) void agg16_lsm(const f16* __restrict__ h3,
                                                 const u32* __restrict__ ecol,
                                                 const u32* __restrict__ row_start,
                                                 const float* __restrict__ dinv,
                                                 const float* __restrict__ bias,
                                                 float* __restrict__ out, int M) {
    int g = threadIdx.x >> 4, l = threadIdx.x & 15;
    int r = blockIdx.x * 16 + g;
    if (r >= M) return;
    u32 beg = row_start[r], end = row_start[r + 1];
    float a0 = 0.f, a1 = 0.f, a2 = 0.f, a3 = 0.f;
    u32 e = beg;
    for (; e + 4 <= end; e += 4) {
        u32 c0 = ecol[e], c1 = ecol[e + 1], c2 = ecol[e + 2], c3 = ecol[e + 3];
        a0 += (float)h3[(size_t)c0 * 16 + l];
        a1 += (float)h3[(size_t)c1 * 16 + l];
        a2 += (float)h3[(size_t)c2 * 16 + l];
        a3 += (float)h3[(size_t)c3 * 16 + l];
    }
    for (; e < end; ++e) a0 += (float)h3[(size_t)ecol[e] * 16 + l];
    float dr = dinv[r];
    float acc = (((a0 + a1) + (a2 + a3)) + (float)h3[(size_t)r * 16 + l]) * dr +
                bias[l];
    float m = acc;
#pragma unroll
    for (int o = 8; o >= 1; o >>= 1) m = fmaxf(m, __shfl_xor(m, o, 16));
    float ex = expf(acc - m);
    float s = ex;
#pragma unroll
    for (int o = 8; o >= 1; o >>= 1) s += __shfl_xor(s, o, 16);
    out[(size_t)r * 16 + l] = acc - m - logf(s);
}

// ---------------- launch ----------------

extern "C" void kernel_launch(void* const* d_in, const int* in_sizes, int n_in,
                              void* d_out, int out_size, void* d_ws, size_t ws_size,
                              hipStream_t stream) {
    const float* x = (const float*)d_in[0];
    const int* ei = (const int*)d_in[1];
    const float* W1 = (const float*)d_in[2];
    const float* b1 = (const float*)d_in[3];
    const float* W2 = (const float*)d_in[4];
    const float* b2 = (const float*)d_in[5];
    const float* W3 = (const float*)d_in[6];
    const float* b3 = (const float*)d_in[7];
    int N = in_sizes[0] / D_IN;
    int E = in_sizes[1] / 2;

    int shift = 0;
    while (((N - 1) >> shift) >= NBUCK) shift++;
    int NB = (E + CHUNK - 1) / CHUNK;  // hist/scatter blocks
    int L = NBUCK * NB;                // Hmat length (bucket-major)

    char* p = (char*)d_ws;
    auto alloc = [&](size_t bytes) -> void* {
        void* q = (void*)p;
        p += (bytes + 255) & ~(size_t)255;
        return q;
    };
    // zeroed region (one memset): cnt | cursor | flag
    u32* cnt = (u32*)alloc((size_t)N * 4);
    u32* cursor = (u32*)alloc((size_t)N * 4);
    u32* flag = (u32*)alloc(256);
    size_t zero_bytes = (size_t)((char*)(flag + 64) - (char*)cnt);
    float* dinv = (float*)alloc((size_t)N * 4);
    u32* row_start = (u32*)alloc((size_t)(N + 1) * 4);
    u32* partial = (u32*)alloc(4096);
    u32* partial2 = (u32*)alloc(4096);
    u32* Hmat = (u32*)alloc((size_t)(L + 1) * 4);
    u32* ecol = (u32*)alloc((size_t)E * 4);
    uint2* bdata = (uint2*)alloc((size_t)E * 8);
    f16* wf1h = (f16*)alloc(16384 * 2);
    f16* wf1l = (f16*)alloc(16384 * 2);
    f16* wf2h = (f16*)alloc(16384 * 2);
    f16* wf2l = (f16*)alloc(16384 * 2);
    f16* wf3h = (f16*)alloc(2048 * 2);
    f16* wf3l = (f16*)alloc(2048 * 2);
    f16* h = (f16*)alloc((size_t)N * 128 * 2);
    f16* act = (f16*)alloc((size_t)N * 128 * 2);
    f16* h3 = (f16*)alloc((size_t)N * 16 * 2);
    (void)ws_size; (void)n_in; (void)out_size;

    hipMemsetAsync(cnt, 0, zero_bytes, stream);

    int nb = (N + 255) / 256;   // 391 <= 512 for scan2
    int nb2 = (L + 255) / 256;  // 25 <= 512

    detect_k<<<32, 256, 0, stream>>>(ei, flag, 8192);
    hist_k<<<NB, 256, 0, stream>>>(ei, flag, Hmat, cnt, E, N, shift, NB);
    // scan Hmat (bucket-major) -> exact global base per (bucket, block)
    scan1<<<nb2, 256, 0, stream>>>(Hmat, Hmat, partial2, L);  // in-place ok: excl then partial
    scan2<<<1, 512, 0, stream>>>(partial2, nb2);
    scan3<<<nb2, 256, 0, stream>>>(Hmat, partial2, L, E);  // sentinel Hmat[L]=E
    // scan cnt -> row_start (+ dinv fused)
    scan1_dinv<<<nb, 256, 0, stream>>>(cnt, row_start, partial, dinv, N);
    scan2<<<1, 512, 0, stream>>>(partial, nb);
    scan3<<<nb, 256, 0, stream>>>(row_start, partial, N, E);

    scatter_bd<<<NB, 256, 0, stream>>>(ei, flag, Hmat, bdata, E, N, shift, NB);
    unbucket_k<<<dim3(512, NBUCK), 256, 0, stream>>>(bdata, Hmat, row_start,
                                                     cursor, ecol, E, NB);

    reformat_all<<<17, 256, 0, stream>>>(W1, W2, W3, wf1h, wf1l, wf2h, wf2l,
                                         wf3h, wf3l);

    int gb = (N + 63) / 64;
    int ab = (N + 3) / 4;
    gemm128_l1<<<gb, 256, 0, stream>>>(x, wf1h, wf1l, dinv, h, N);
    agg128<<<ab, 256, 0, stream>>>(h, ecol, row_start, dinv, b1, act, N);
    gemm128_l2<<<gb, 256, 0, stream>>>(act, wf2h, wf2l, h, N);
    agg128<<<ab, 256, 0, stream>>>(h, ecol, row_start, dinv, b2, act, N);
    gemm16<<<gb, 256, 0, stream>>>(act, wf3h, wf3l, h3, N);
    agg16_lsm<<<(N + 15) / 16, 256, 0, stream>>>(h3, ecol, row_start, dinv, b3,
                                                 (float*)d_out, N);
}

// Round 7
// 487.442 us; speedup vs baseline: 1.2044x; 1.0087x over previous
//
#include <hip/hip_runtime.h>

typedef unsigned int u32;
typedef _Float16 f16;
typedef __attribute__((ext_vector_type(8))) _Float16 half8;
typedef __attribute__((ext_vector_type(2))) _Float16 half2_t;
typedef __attribute__((ext_vector_type(4))) float f32x4;

#define D_IN 128
#define D_HID 128
#define D_OUT 16
#define NBUCK 8
#define CHUNK 2048  // edges per hist/scatter block (256 thr x 8)

// ---------------- preprocessing ----------------

// flag: 1 if edge_index is int32 layout, 0 if int64 (odd words all zero).
__global__ __launch_bounds__(256) void detect_k(const int* __restrict__ ei,
                                                u32* __restrict__ flag, int n) {
    int i = blockIdx.x * 256 + threadIdx.x;
    if (i < n && (i & 1) && ei[i] != 0) atomicOr(flag, 1u);
}

__device__ inline int load_row(const int* ei, u32 f, int e, int E) {
    return f ? ei[e] : ei[2 * e];
}
__device__ inline int load_col(const int* ei, u32 f, int e, int E) {
    return f ? ei[E + e] : ei[2 * E + 2 * e];
}
__device__ inline int clampi(int v, int n) {
    v = v < 0 ? 0 : v;
    return v >= n ? n - 1 : v;
}

// Per-block bucket histogram (bucket-major matrix, plain stores — no global
// return-atomics) + fire-and-forget degree count.
__global__ __launch_bounds__(256) void hist_k(const int* __restrict__ ei,
                                              const u32* __restrict__ flag,
                                              u32* __restrict__ Hmat,
                                              u32* __restrict__ cnt,
                                              int E, int N, int shift, int NB) {
    __shared__ u32 lh[NBUCK];
    int tid = threadIdx.x;
    if (tid < NBUCK) lh[tid] = 0;
    __syncthreads();
    u32 f = *flag;
    int base = blockIdx.x * CHUNK;
#pragma unroll
    for (int j = 0; j < CHUNK / 256; j++) {
        int e = base + j * 256 + tid;
        if (e < E) {
            int r = clampi(load_row(ei, f, e, E), N);
            atomicAdd(&lh[(u32)r >> shift], 1u);
            atomicAdd(&cnt[r], 1u);
        }
    }
    __syncthreads();
    if (tid < NBUCK) Hmat[(size_t)tid * NB + blockIdx.x] = lh[tid];
}

__global__ __launch_bounds__(256) void scan1(const u32* __restrict__ cnt,
                                             u32* __restrict__ excl,
                                             u32* __restrict__ partial, int n) {
    __shared__ u32 sm[256];
    int tid = threadIdx.x;
    int i = blockIdx.x * 256 + tid;
    u32 v = (i < n) ? cnt[i] : 0u;
    sm[tid] = v;
    __syncthreads();
    for (int off = 1; off < 256; off <<= 1) {
        u32 t = (tid >= off) ? sm[tid - off] : 0u;
        __syncthreads();
        sm[tid] += t;
        __syncthreads();
    }
    if (i < n) excl[i] = sm[tid] - v;
    if (tid == 255) partial[blockIdx.x] = sm[255];
}

// scan1 variant that also emits dinv = rsqrt(deg+1) (fuses old dinv_k).
__global__ __launch_bounds__(256) void scan1_dinv(const u32* __restrict__ cnt,
                                                  u32* __restrict__ excl,
                                                  u32* __restrict__ partial,
                                                  float* __restrict__ dinv, int n) {
    __shared__ u32 sm[256];
    int tid = threadIdx.x;
    int i = blockIdx.x * 256 + tid;
    u32 v = (i < n) ? cnt[i] : 0u;
    if (i < n) dinv[i] = rsqrtf((float)(v + 1u));  // +1 self loop
    sm[tid] = v;
    __syncthreads();
    for (int off = 1; off < 256; off <<= 1) {
        u32 t = (tid >= off) ? sm[tid - off] : 0u;
        __syncthreads();
        sm[tid] += t;
        __syncthreads();
    }
    if (i < n) excl[i] = sm[tid] - v;
    if (tid == 255) partial[blockIdx.x] = sm[255];
}

__global__ __launch_bounds__(512) void scan2(u32* __restrict__ partial, int nb) {
    __shared__ u32 sm[512];
    int tid = threadIdx.x;
    u32 v = (tid < nb) ? partial[tid] : 0u;
    sm[tid] = v;
    __syncthreads();
    for (int off = 1; off < 512; off <<= 1) {
        u32 t = (tid >= off) ? sm[tid - off] : 0u;
        __syncthreads();
        sm[tid] += t;
        __syncthreads();
    }
    if (tid < nb) partial[tid] = sm[tid] - v;
}

__global__ __launch_bounds__(256) void scan3(u32* __restrict__ excl,
                                             const u32* __restrict__ partial,
                                             int n, int E) {
    int i = blockIdx.x * 256 + threadIdx.x;
    if (i < n) excl[i] += partial[blockIdx.x];
    if (i == 0) excl[n] = (u32)E;
}

// Re-read edges; each block's run positions are exact (Hbase), so only
// block-local LDS atomics are needed. Writes dense (r,c) records, bucket-major.
__global__ __launch_bounds__(256) void scatter_bd(const int* __restrict__ ei,
                                                  const u32* __restrict__ flag,
                                                  const u32* __restrict__ Hbase,
                                                  uint2* __restrict__ bdata,
                                                  int E, int N, int shift, int NB) {
    __shared__ u32 lbase[NBUCK];
    int tid = threadIdx.x;
    if (tid < NBUCK) lbase[tid] = Hbase[(size_t)tid * NB + blockIdx.x];
    __syncthreads();
    u32 f = *flag;
    int base = blockIdx.x * CHUNK;
#pragma unroll
    for (int j = 0; j < CHUNK / 256; j++) {
        int e = base + j * 256 + tid;
        if (e < E) {
            int r = clampi(load_row(ei, f, e, E), N);
            int c = clampi(load_col(ei, f, e, E), N);
            u32 pos = atomicAdd(&lbase[(u32)r >> shift], 1u);
            if (pos < (u32)E) bdata[pos] = make_uint2((u32)r, (u32)c);
        }
    }
}

// XCD-affine unbucket: bucket = blockIdx.x & 7 so (with the round-robin
// block->XCD dispatch) all blocks touching bucket b's ~800KB ecol window and
// ~50KB cursor window live on ONE XCD -> lines are fully assembled in that L2
// before writeback (kills the 15x write amplification seen when all buckets
// ran across all XCDs concurrently).
__global__ __launch_bounds__(256) void unbucket_k(const uint2* __restrict__ bdata,
                                                  const u32* __restrict__ Hbase,
                                                  const u32* __restrict__ row_start,
                                                  u32* __restrict__ cursor,
                                                  u32* __restrict__ ecol,
                                                  int E, int NB, int slices) {
    int b = blockIdx.x & (NBUCK - 1);
    int slice = blockIdx.x >> 3;
    u32 s = Hbase[(size_t)b * NB];
    u32 t = Hbase[(size_t)(b + 1) * NB];  // b=7 hits sentinel Hbase[8*NB]=E
    u32 stride = (u32)slices * 256u;
    for (u32 i = s + slice * 256 + threadIdx.x; i < t; i += stride) {
        uint2 rc = bdata[i];
        u32 pos = row_start[rc.x] + atomicAdd(&cursor[rc.x], 1u);
        if (pos < (u32)E) ecol[pos] = rc.y;
    }
}

// Split fp32 W into hi/lo f16 MFMA B-fragments. One dispatch covers all three
// weight matrices: blocks 0-7 -> W1, 8-15 -> W2, 16 -> W3.
__global__ __launch_bounds__(256) void reformat_all(const float* __restrict__ W1,
                                                    const float* __restrict__ W2,
                                                    const float* __restrict__ W3,
                                                    f16* __restrict__ W1h, f16* __restrict__ W1l,
                                                    f16* __restrict__ W2h, f16* __restrict__ W2l,
                                                    f16* __restrict__ W3h, f16* __restrict__ W3l) {
    const float* W;
    f16 *Wh, *Wl;
    int ntiles, bidx;
    if (blockIdx.x < 8) { W = W1; Wh = W1h; Wl = W1l; ntiles = 8; bidx = blockIdx.x; }
    else if (blockIdx.x < 16) { W = W2; Wh = W2h; Wl = W2l; ntiles = 8; bidx = blockIdx.x - 8; }
    else { W = W3; Wh = W3h; Wl = W3l; ntiles = 1; bidx = 0; }
    int idx = bidx * 256 + threadIdx.x;
    int total = 4 * ntiles * 64;
    if (idx >= total) return;
    int lane = idx & 63;
    int st = idx >> 6;
    int t = st % ntiles;
    int s = st / ntiles;
    int Nc = ntiles * 16;
    int n = t * 16 + (lane & 15);
    int kb = lane >> 4;
    half8 vh, vl;
#pragma unroll
    for (int j = 0; j < 8; j++) {
        float w = W[(size_t)(s * 32 + kb * 8 + j) * Nc + n];
        f16 hi = (f16)w;
        f16 lo = (f16)(w - (float)hi);
        vh[j] = hi;
        vl[j] = lo;
    }
    *(half8*)(Wh + (size_t)idx * 8) = vh;
    *(half8*)(Wl + (size_t)idx * 8) = vl;
}

// ---------------- GEMMs (f16 MFMA 16x16x32, fp32-accurate via splits) --------

// Layer 1: A fp32 [M x 128]; 3 MFMAs; epilogue scales row rr by dinv[rr]
// so the stored table is h' = (x@W1)*dinv  (norm folded into storage).
__global__ __launch_bounds__(256) void gemm128_l1(const float* __restrict__ A,
                                                  const f16* __restrict__ Wh,
                                                  const f16* __restrict__ Wl,
                                                  const float* __restrict__ dinv,
                                                  f16* __restrict__ H, int M) {
    int wave = threadIdx.x >> 6, lane = threadIdx.x & 63;
    int mbase = blockIdx.x * 64 + wave * 16;
    int mload = mbase + (lane & 15);
    if (mload >= M) mload = M - 1;
    int kq = lane >> 4;
    f32x4 acc[8];
#pragma unroll
    for (int t = 0; t < 8; t++) acc[t] = (f32x4){0.f, 0.f, 0.f, 0.f};
#pragma unroll
    for (int s = 0; s < 4; s++) {
        const float* ap = A + (size_t)mload * 128 + s * 32 + kq * 8;
        half8 ah, al;
#pragma unroll
        for (int j = 0; j < 8; j++) {
            float v = ap[j];
            f16 hi = (f16)v;
            ah[j] = hi;
            al[j] = (f16)(v - (float)hi);
        }
#pragma unroll
        for (int t = 0; t < 8; t++) {
            half8 bh = *(const half8*)(Wh + (size_t)((s * 8 + t) * 64 + lane) * 8);
            half8 bl = *(const half8*)(Wl + (size_t)((s * 8 + t) * 64 + lane) * 8);
            acc[t] = __builtin_amdgcn_mfma_f32_16x16x32_f16(ah, bh, acc[t], 0, 0, 0);
            acc[t] = __builtin_amdgcn_mfma_f32_16x16x32_f16(ah, bl, acc[t], 0, 0, 0);
            acc[t] = __builtin_amdgcn_mfma_f32_16x16x32_f16(al, bh, acc[t], 0, 0, 0);
        }
    }
    int coln = lane & 15;
    int rbase = mbase + ((lane >> 4) << 2);
    float dsc[4];
#pragma unroll
    for (int i = 0; i < 4; i++) {
        int rr = rbase + i;
        dsc[i] = dinv[rr < M ? rr : M - 1];
    }
#pragma unroll
    for (int t = 0; t < 8; t++) {
#pragma unroll
        for (int i = 0; i < 4; i++) {
            int rr = rbase + i;
            if (rr < M) H[(size_t)rr * 128 + t * 16 + coln] = (f16)(acc[t][i] * dsc[i]);
        }
    }
}

// Layer 2: A f16 (pre-scaled act') [M x 128]; 2 MFMAs; output inherits the
// dinv row-scale automatically ((act*dinv)@W = (act@W)*dinv).
__global__ __launch_bounds__(256) void gemm128_l2(const f16* __restrict__ A,
                                                  const f16* __restrict__ Wh,
                                                  const f16* __restrict__ Wl,
                                                  f16* __restrict__ H, int M) {
    int wave = threadIdx.x >> 6, lane = threadIdx.x & 63;
    int mbase = blockIdx.x * 64 + wave * 16;
    int mload = mbase + (lane & 15);
    if (mload >= M) mload = M - 1;
    int kq = lane >> 4;
    f32x4 acc[8];
#pragma unroll
    for (int t = 0; t < 8; t++) acc[t] = (f32x4){0.f, 0.f, 0.f, 0.f};
#pragma unroll
    for (int s = 0; s < 4; s++) {
        half8 a = *(const half8*)(A + (size_t)mload * 128 + s * 32 + kq * 8);
#pragma unroll
        for (int t = 0; t < 8; t++) {
            half8 bh = *(const half8*)(Wh + (size_t)((s * 8 + t) * 64 + lane) * 8);
            half8 bl = *(const half8*)(Wl + (size_t)((s * 8 + t) * 64 + lane) * 8);
            acc[t] = __builtin_amdgcn_mfma_f32_16x16x32_f16(a, bh, acc[t], 0, 0, 0);
            acc[t] = __builtin_amdgcn_mfma_f32_16x16x32_f16(a, bl, acc[t], 0, 0, 0);
        }
    }
    int coln = lane & 15;
    int rbase = mbase + ((lane >> 4) << 2);
#pragma unroll
    for (int t = 0; t < 8; t++) {
#pragma unroll
        for (int i = 0; i < 4; i++) {
            int rr = rbase + i;
            if (rr < M) H[(size_t)rr * 128 + t * 16 + coln] = (f16)acc[t][i];
        }
    }
}

// Layer 3: A f16 (pre-scaled) [M x 128] -> H3' f16 [M x 16].
__global__ __launch_bounds__(256) void gemm16(const f16* __restrict__ A,
                                              const f16* __restrict__ Wh,
                                              const f16* __restrict__ Wl,
                                              f16* __restrict__ H, int M) {
    int wave = threadIdx.x >> 6, lane = threadIdx.x & 63;
    int mbase = blockIdx.x * 64 + wave * 16;
    int mload = mbase + (lane & 15);
    if (mload >= M) mload = M - 1;
    int kq = lane >> 4;
    f32x4 acc = (f32x4){0.f, 0.f, 0.f, 0.f};
#pragma unroll
    for (int s = 0; s < 4; s++) {
        half8 a = *(const half8*)(A + (size_t)mload * 128 + s * 32 + kq * 8);
        half8 bh = *(const half8*)(Wh + (size_t)(s * 64 + lane) * 8);
        half8 bl = *(const half8*)(Wl + (size_t)(s * 64 + lane) * 8);
        acc = __builtin_amdgcn_mfma_f32_16x16x32_f16(a, bh, acc, 0, 0, 0);
        acc = __builtin_amdgcn_mfma_f32_16x16x32_f16(a, bl, acc, 0, 0, 0);
    }
    int coln = lane & 15;
    int rbase = mbase + ((lane >> 4) << 2);
#pragma unroll
    for (int i = 0; i < 4; i++) {
        int rr = rbase + i;
        if (rr < M) H[(size_t)rr * 16 + coln] = (f16)acc[i];
    }
}

// ---------------- aggregation ----------------
// One wave per row; lane handles features 2*lane, 2*lane+1 (half2, 4B/lane ->
// one coalesced 256B gather per edge). Unroll 16 for MLP.
// out = relu(dinv[r]*(sum h'[c] + h'[r]) + b) * dinv[r]   (h' pre-scaled).
__global__ __launch_bounds__(256) void agg128(const f16* __restrict__ h,
                                              const u32* __restrict__ ecol,
                                              const u32* __restrict__ row_start,
                                              const float* __restrict__ dinv,
                                              const float* __restrict__ bias,
                                              f16* __restrict__ out, int M) {
    int wave = threadIdx.x >> 6, lane = threadIdx.x & 63;
    int r = blockIdx.x * 4 + wave;
    if (r >= M) return;
    u32 beg = row_start[r], end = row_start[r + 1];
    const half2_t* hp = (const half2_t*)h;
    float ax0 = 0, ay0 = 0, ax1 = 0, ay1 = 0, ax2 = 0, ay2 = 0, ax3 = 0, ay3 = 0;
    u32 e = beg;
    for (; e + 16 <= end; e += 16) {
        u32 c[16];
#pragma unroll
        for (int j = 0; j < 16; j++) c[j] = ecol[e + j];
        half2_t v[16];
#pragma unroll
        for (int j = 0; j < 16; j++) v[j] = hp[(size_t)c[j] * 64 + lane];
#pragma unroll
        for (int j = 0; j < 16; j += 4) {
            ax0 += (float)v[j][0];     ay0 += (float)v[j][1];
            ax1 += (float)v[j + 1][0]; ay1 += (float)v[j + 1][1];
            ax2 += (float)v[j + 2][0]; ay2 += (float)v[j + 2][1];
            ax3 += (float)v[j + 3][0]; ay3 += (float)v[j + 3][1];
        }
    }
    for (; e + 4 <= end; e += 4) {
        u32 c0 = ecol[e], c1 = ecol[e + 1], c2 = ecol[e + 2], c3 = ecol[e + 3];
        half2_t v0 = hp[(size_t)c0 * 64 + lane];
        half2_t v1 = hp[(size_t)c1 * 64 + lane];
        half2_t v2 = hp[(size_t)c2 * 64 + lane];
        half2_t v3 = hp[(size_t)c3 * 64 + lane];
        ax0 += (float)v0[0]; ay0 += (float)v0[1];
        ax1 += (float)v1[0]; ay1 += (float)v1[1];
        ax2 += (float)v2[0]; ay2 += (float)v2[1];
        ax3 += (float)v3[0]; ay3 += (float)v3[1];
    }
    for (; e < end; ++e) {
        half2_t v = hp[(size_t)ecol[e] * 64 + lane];
        ax0 += (float)v[0]; ay0 += (float)v[1];
    }
    half2_t vs = hp[(size_t)r * 64 + lane];
    float dr = dinv[r];
    float2 bb = ((const float2*)bias)[lane];
    float ax = (((ax0 + ax1) + (ax2 + ax3)) + (float)vs[0]) * dr + bb.x;
    float ay = (((ay0 + ay1) + (ay2 + ay3)) + (float)vs[1]) * dr + bb.y;
    ax = fmaxf(ax, 0.f) * dr;  // pre-scale for next layer's gather
    ay = fmaxf(ay, 0.f) * dr;
    half2_t o;
    o[0] = (f16)ax;
    o[1] = (f16)ay;
    ((half2_t*)out)[(size_t)r * 64 + lane] = o;
}

// 16 lanes per row; h3' pre-scaled; fused bias + log_softmax; fp32 output.
__global__ __launch_bounds__(256) void agg16_lsm(const f16* __restrict__ h3,
                                                 const u32* __restrict__ ecol,
                                                 const u32* __restrict__ row_start,
                                                 const float* __restrict__ dinv,
                                                 const float* __restrict__ bias,
                                                 float* __restrict__ out, int M) {
    int g = threadIdx.x >> 4, l = threadIdx.x & 15;
    int r = blockIdx.x * 16 + g;
    if (r >= M) return;
    u32 beg = row_start[r], end = row_start[r + 1];
    float a0 = 0.f, a1 = 0.f, a2 = 0.f, a3 = 0.f;
    u32 e = beg;
    for (; e + 4 <= end; e += 4) {
        u32 c0 = ecol[e], c1 = ecol[e + 1], c2 = ecol[e + 2], c3 = ecol[e + 3];
        a0 += (float)h3[(size_t)c0 * 16 + l];
        a1 += (float)h3[(size_t)c1 * 16 + l];
        a2 += (float)h3[(size_t)c2 * 16 + l];
        a3 += (float)h3[(size_t)c3 * 16 + l];
    }
    for (; e < end; ++e) a0 += (float)h3[(size_t)ecol[e] * 16 + l];
    float dr = dinv[r];
    float acc = (((a0 + a1) + (a2 + a3)) + (float)h3[(size_t)r * 16 + l]) * dr +
                bias[l];
    float m = acc;
#pragma unroll
    for (int o = 8; o >= 1; o >>= 1) m = fmaxf(m, __shfl_xor(m, o, 16));
    float ex = expf(acc - m);
    float s = ex;
#pragma unroll
    for (int o = 8; o >= 1; o >>= 1) s += __shfl_xor(s, o, 16);
    out[(size_t)r * 16 + l] = acc - m - logf(s);
}

// ---------------- launch ----------------

extern "C" void kernel_launch(void* const* d_in, const int* in_sizes, int n_in,
                              void* d_out, int out_size, void* d_ws, size_t ws_size,
                              hipStream_t stream) {
    const float* x = (const float*)d_in[0];
    const int* ei = (const int*)d_in[1];
    const float* W1 = (const float*)d_in[2];
    const float* b1 = (const float*)d_in[3];
    const float* W2 = (const float*)d_in[4];
    const float* b2 = (const float*)d_in[5];
    const float* W3 = (const float*)d_in[6];
    const float* b3 = (const float*)d_in[7];
    int N = in_sizes[0] / D_IN;
    int E = in_sizes[1] / 2;

    int shift = 0;
    while (((N - 1) >> shift) >= NBUCK) shift++;
    int NB = (E + CHUNK - 1) / CHUNK;  // hist/scatter blocks
    int L = NBUCK * NB;                // Hmat length (bucket-major)

    char* p = (char*)d_ws;
    auto alloc = [&](size_t bytes) -> void* {
        void* q = (void*)p;
        p += (bytes + 255) & ~(size_t)255;
        return q;
    };
    // zeroed region (one memset): cnt | cursor | flag
    u32* cnt = (u32*)alloc((size_t)N * 4);
    u32* cursor = (u32*)alloc((size_t)N * 4);
    u32* flag = (u32*)alloc(256);
    size_t zero_bytes = (size_t)((char*)(flag + 64) - (char*)cnt);
    float* dinv = (float*)alloc((size_t)N * 4);
    u32* row_start = (u32*)alloc((size_t)(N + 1) * 4);
    u32* partial = (u32*)alloc(4096);
    u32* partial2 = (u32*)alloc(4096);
    u32* Hmat = (u32*)alloc((size_t)(L + 1) * 4);
    u32* ecol = (u32*)alloc((size_t)E * 4);
    uint2* bdata = (uint2*)alloc((size_t)E * 8);
    f16* wf1h = (f16*)alloc(16384 * 2);
    f16* wf1l = (f16*)alloc(16384 * 2);
    f16* wf2h = (f16*)alloc(16384 * 2);
    f16* wf2l = (f16*)alloc(16384 * 2);
    f16* wf3h = (f16*)alloc(2048 * 2);
    f16* wf3l = (f16*)alloc(2048 * 2);
    f16* h = (f16*)alloc((size_t)N * 128 * 2);
    f16* act = (f16*)alloc((size_t)N * 128 * 2);
    f16* h3 = (f16*)alloc((size_t)N * 16 * 2);
    (void)ws_size; (void)n_in; (void)out_size;

    hipMemsetAsync(cnt, 0, zero_bytes, stream);

    int nb = (N + 255) / 256;   // 391 <= 512 for scan2
    int nb2 = (L + 255) / 256;  // 25 <= 512

    detect_k<<<32, 256, 0, stream>>>(ei, flag, 8192);
    hist_k<<<NB, 256, 0, stream>>>(ei, flag, Hmat, cnt, E, N, shift, NB);
    // scan Hmat (bucket-major) -> exact global base per (bucket, block)
    scan1<<<nb2, 256, 0, stream>>>(Hmat, Hmat, partial2, L);
    scan2<<<1, 512, 0, stream>>>(partial2, nb2);
    scan3<<<nb2, 256, 0, stream>>>(Hmat, partial2, L, E);  // sentinel Hmat[L]=E
    // scan cnt -> row_start (+ dinv fused)
    scan1_dinv<<<nb, 256, 0, stream>>>(cnt, row_start, partial, dinv, N);
    scan2<<<1, 512, 0, stream>>>(partial, nb);
    scan3<<<nb, 256, 0, stream>>>(row_start, partial, N, E);

    scatter_bd<<<NB, 256, 0, stream>>>(ei, flag, Hmat, bdata, E, N, shift, NB);
    int slices = 512;
    unbucket_k<<<slices * NBUCK, 256, 0, stream>>>(bdata, Hmat, row_start,
                                                   cursor, ecol, E, NB, slices);

    reformat_all<<<17, 256, 0, stream>>>(W1, W2, W3, wf1h, wf1l, wf2h, wf2l,
                                         wf3h, wf3l);

    int gb = (N + 63) / 64;
    int ab = (N + 3) / 4;
    gemm128_l1<<<gb, 256, 0, stream>>>(x, wf1h, wf1l, dinv, h, N);
    agg128<<<ab, 256, 0, stream>>>(h, ecol, row_start, dinv, b1, act, N);
    gemm128_l2<<<gb, 256, 0, stream>>>(act, wf2h, wf2l, h, N);
    agg128<<<ab, 256, 0, stream>>>(h, ecol, row_start, dinv, b2, act, N);
    gemm16<<<gb, 256, 0, stream>>>(act, wf3h, wf3l, h3, N);
    agg16_lsm<<<(N + 15) / 16, 256, 0, stream>>>(h3, ecol, row_start, dinv, b3,
                                                 (float*)d_out, N);
}

// Round 8
// 404.297 us; speedup vs baseline: 1.4521x; 1.2057x over previous
//
#include <hip/hip_runtime.h>

typedef unsigned int u32;
typedef _Float16 f16;
typedef __attribute__((ext_vector_type(8))) _Float16 half8;
typedef __attribute__((ext_vector_type(2))) _Float16 half2_t;
typedef __attribute__((ext_vector_type(4))) float f32x4;

#define D_IN 128
#define D_HID 128
#define D_OUT 16
#define RPB 128        // rows per bucket (lr fits in 7 bits; c < 2^20)
#define MAXBUCK 1024   // supports N <= 131072
#define CHUNK 16384    // edges per hist/scatter block (256 thr x 64)

// ---------------- preprocessing ----------------

// flag: 1 if edge_index is int32 layout, 0 if int64 (odd words all zero).
__global__ __launch_bounds__(256) void detect_k(const int* __restrict__ ei,
                                                u32* __restrict__ flag, int n) {
    int i = blockIdx.x * 256 + threadIdx.x;
    if (i < n && (i & 1) && ei[i] != 0) atomicOr(flag, 1u);
}

__device__ inline int load_row(const int* ei, u32 f, int e, int E) {
    return f ? ei[e] : ei[2 * e];
}
__device__ inline int load_col(const int* ei, u32 f, int e, int E) {
    return f ? ei[E + e] : ei[2 * E + 2 * e];
}
__device__ inline int clampi(int v, int n) {
    v = v < 0 ? 0 : v;
    return v >= n ? n - 1 : v;
}

// Pass 1: per-block histogram over row-buckets (bucket-major Hmat, plain
// stores — no global atomics at all).
__global__ __launch_bounds__(256) void hist_k(const int* __restrict__ ei,
                                              const u32* __restrict__ flag,
                                              u32* __restrict__ Hmat,
                                              int E, int N, int NBK, int NB) {
    __shared__ u32 lh[MAXBUCK];
    int tid = threadIdx.x;
    for (int i = tid; i < NBK; i += 256) lh[i] = 0;
    __syncthreads();
    u32 f = *flag;
    int base = blockIdx.x * CHUNK;
    int lim = base + CHUNK < E ? base + CHUNK : E;
    for (int e = base + tid; e < lim; e += 256) {
        int r = clampi(load_row(ei, f, e, E), N);
        atomicAdd(&lh[(u32)r >> 7], 1u);
    }
    __syncthreads();
    for (int i = tid; i < NBK; i += 256)
        Hmat[(size_t)i * NB + blockIdx.x] = lh[i];
}

__global__ __launch_bounds__(256) void scan1(const u32* __restrict__ cnt,
                                             u32* __restrict__ excl,
                                             u32* __restrict__ partial, int n) {
    __shared__ u32 sm[256];
    int tid = threadIdx.x;
    int i = blockIdx.x * 256 + tid;
    u32 v = (i < n) ? cnt[i] : 0u;
    sm[tid] = v;
    __syncthreads();
    for (int off = 1; off < 256; off <<= 1) {
        u32 t = (tid >= off) ? sm[tid - off] : 0u;
        __syncthreads();
        sm[tid] += t;
        __syncthreads();
    }
    if (i < n) excl[i] = sm[tid] - v;
    if (tid == 255) partial[blockIdx.x] = sm[255];
}

__global__ __launch_bounds__(512) void scan2(u32* __restrict__ partial, int nb) {
    __shared__ u32 sm[512];
    int tid = threadIdx.x;
    u32 v = (tid < nb) ? partial[tid] : 0u;
    sm[tid] = v;
    __syncthreads();
    for (int off = 1; off < 512; off <<= 1) {
        u32 t = (tid >= off) ? sm[tid - off] : 0u;
        __syncthreads();
        sm[tid] += t;
        __syncthreads();
    }
    if (tid < nb) partial[tid] = sm[tid] - v;
}

__global__ __launch_bounds__(256) void scan3(u32* __restrict__ excl,
                                             const u32* __restrict__ partial,
                                             int n, int E) {
    int i = blockIdx.x * 256 + threadIdx.x;
    if (i < n) excl[i] += partial[blockIdx.x];
    if (i == 0) excl[n] = (u32)E;
}

// Pass 2: re-read edges; block-exact frontiers per bucket (from scanned Hmat),
// only LDS atomics. Record = (r&127)<<20 | c (u32, c < 2^20).
__global__ __launch_bounds__(256) void scatter_bd(const int* __restrict__ ei,
                                                  const u32* __restrict__ flag,
                                                  const u32* __restrict__ Hbase,
                                                  u32* __restrict__ bdata,
                                                  int E, int N, int NBK, int NB) {
    __shared__ u32 lbase[MAXBUCK];
    int tid = threadIdx.x;
    for (int i = tid; i < NBK; i += 256)
        lbase[i] = Hbase[(size_t)i * NB + blockIdx.x];
    __syncthreads();
    u32 f = *flag;
    int base = blockIdx.x * CHUNK;
    int lim = base + CHUNK < E ? base + CHUNK : E;
    for (int e = base + tid; e < lim; e += 256) {
        int r = clampi(load_row(ei, f, e, E), N);
        int c = clampi(load_col(ei, f, e, E), N);
        u32 pos = atomicAdd(&lbase[(u32)r >> 7], 1u);
        if (pos < (u32)E) bdata[pos] = ((u32)(r & (RPB - 1)) << 20) | (u32)c;
    }
}

// Pass 3: one block per bucket (128 rows, private contiguous record range
// [s,t)). Computes per-row degree + exclusive scan in LDS -> writes row_start
// and dinv, then scatters cols into the bucket's private ~8KB ecol window with
// LDS cursors. No global atomics; no cross-block window sharing.
__global__ __launch_bounds__(256) void finalize_k(const u32* __restrict__ bdata,
                                                  const u32* __restrict__ Hbase,
                                                  u32* __restrict__ row_start,
                                                  float* __restrict__ dinv,
                                                  u32* __restrict__ ecol,
                                                  int N, int E, int NB) {
    __shared__ u32 smc[RPB];
    __shared__ u32 cur[RPB];
    int b = blockIdx.x;
    int tid = threadIdx.x;
    u32 s = Hbase[(size_t)b * NB];
    u32 t = Hbase[(size_t)(b + 1) * NB];  // last bucket hits sentinel = E
    if (tid < RPB) smc[tid] = 0;
    __syncthreads();
    for (u32 i = s + tid; i < t; i += 256)
        atomicAdd(&smc[bdata[i] >> 20], 1u);
    __syncthreads();
    u32 myc = (tid < RPB) ? smc[tid] : 0;
    for (int off = 1; off < RPB; off <<= 1) {
        u32 tv = (tid < RPB && tid >= off) ? smc[tid - off] : 0u;
        __syncthreads();
        if (tid < RPB) smc[tid] += tv;
        __syncthreads();
    }
    if (tid < RPB) {
        u32 excl = smc[tid] - myc;
        int r = b * RPB + tid;
        if (r < N) {
            row_start[r] = s + excl;
            dinv[r] = rsqrtf((float)(myc + 1u));  // +1 self loop
        }
        cur[tid] = s + excl;
    }
    if (b == 0 && tid == 0) row_start[N] = (u32)E;
    __syncthreads();
    for (u32 i = s + tid; i < t; i += 256) {
        u32 rec = bdata[i];
        u32 pos = atomicAdd(&cur[rec >> 20], 1u);
        if (pos < (u32)E) ecol[pos] = rec & 0xFFFFFu;
    }
}

// Split fp32 W into hi/lo f16 MFMA B-fragments. One dispatch covers all three
// weight matrices: blocks 0-7 -> W1, 8-15 -> W2, 16 -> W3.
__global__ __launch_bounds__(256) void reformat_all(const float* __restrict__ W1,
                                                    const float* __restrict__ W2,
                                                    const float* __restrict__ W3,
                                                    f16* __restrict__ W1h, f16* __restrict__ W1l,
                                                    f16* __restrict__ W2h, f16* __restrict__ W2l,
                                                    f16* __restrict__ W3h, f16* __restrict__ W3l) {
    const float* W;
    f16 *Wh, *Wl;
    int ntiles, bidx;
    if (blockIdx.x < 8) { W = W1; Wh = W1h; Wl = W1l; ntiles = 8; bidx = blockIdx.x; }
    else if (blockIdx.x < 16) { W = W2; Wh = W2h; Wl = W2l; ntiles = 8; bidx = blockIdx.x - 8; }
    else { W = W3; Wh = W3h; Wl = W3l; ntiles = 1; bidx = 0; }
    int idx = bidx * 256 + threadIdx.x;
    int total = 4 * ntiles * 64;
    if (idx >= total) return;
    int lane = idx & 63;
    int st = idx >> 6;
    int t = st % ntiles;
    int s = st / ntiles;
    int Nc = ntiles * 16;
    int n = t * 16 + (lane & 15);
    int kb = lane >> 4;
    half8 vh, vl;
#pragma unroll
    for (int j = 0; j < 8; j++) {
        float w = W[(size_t)(s * 32 + kb * 8 + j) * Nc + n];
        f16 hi = (f16)w;
        f16 lo = (f16)(w - (float)hi);
        vh[j] = hi;
        vl[j] = lo;
    }
    *(half8*)(Wh + (size_t)idx * 8) = vh;
    *(half8*)(Wl + (size_t)idx * 8) = vl;
}

// ---------------- GEMMs (f16 MFMA 16x16x32, fp32-accurate via splits) --------

// Layer 1: A fp32 [M x 128]; 3 MFMAs; epilogue scales row rr by dinv[rr]
// so the stored table is h' = (x@W1)*dinv  (norm folded into storage).
__global__ __launch_bounds__(256) void gemm128_l1(const float* __restrict__ A,
                                                  const f16* __restrict__ Wh,
                                                  const f16* __restrict__ Wl,
                                                  const float* __restrict__ dinv,
                                                  f16* __restrict__ H, int M) {
    int wave = threadIdx.x >> 6, lane = threadIdx.x & 63;
    int mbase = blockIdx.x * 64 + wave * 16;
    int mload = mbase + (lane & 15);
    if (mload >= M) mload = M - 1;
    int kq = lane >> 4;
    f32x4 acc[8];
#pragma unroll
    for (int t = 0; t < 8; t++) acc[t] = (f32x4){0.f, 0.f, 0.f, 0.f};
#pragma unroll
    for (int s = 0; s < 4; s++) {
        const float* ap = A + (size_t)mload * 128 + s * 32 + kq * 8;
        half8 ah, al;
#pragma unroll
        for (int j = 0; j < 8; j++) {
            float v = ap[j];
            f16 hi = (f16)v;
            ah[j] = hi;
            al[j] = (f16)(v - (float)hi);
        }
#pragma unroll
        for (int t = 0; t < 8; t++) {
            half8 bh = *(const half8*)(Wh + (size_t)((s * 8 + t) * 64 + lane) * 8);
            half8 bl = *(const half8*)(Wl + (size_t)((s * 8 + t) * 64 + lane) * 8);
            acc[t] = __builtin_amdgcn_mfma_f32_16x16x32_f16(ah, bh, acc[t], 0, 0, 0);
            acc[t] = __builtin_amdgcn_mfma_f32_16x16x32_f16(ah, bl, acc[t], 0, 0, 0);
            acc[t] = __builtin_amdgcn_mfma_f32_16x16x32_f16(al, bh, acc[t], 0, 0, 0);
        }
    }
    int coln = lane & 15;
    int rbase = mbase + ((lane >> 4) << 2);
    float dsc[4];
#pragma unroll
    for (int i = 0; i < 4; i++) {
        int rr = rbase + i;
        dsc[i] = dinv[rr < M ? rr : M - 1];
    }
#pragma unroll
    for (int t = 0; t < 8; t++) {
#pragma unroll
        for (int i = 0; i < 4; i++) {
            int rr = rbase + i;
            if (rr < M) H[(size_t)rr * 128 + t * 16 + coln] = (f16)(acc[t][i] * dsc[i]);
        }
    }
}

// Layer 2: A f16 (pre-scaled act') [M x 128]; 2 MFMAs; output inherits the
// dinv row-scale automatically ((act*dinv)@W = (act@W)*dinv).
__global__ __launch_bounds__(256) void gemm128_l2(const f16* __restrict__ A,
                                                  const f16* __restrict__ Wh,
                                                  const f16* __restrict__ Wl,
                                                  f16* __restrict__ H, int M) {
    int wave = threadIdx.x >> 6, lane = threadIdx.x & 63;
    int mbase = blockIdx.x * 64 + wave * 16;
    int mload = mbase + (lane & 15);
    if (mload >= M) mload = M - 1;
    int kq = lane >> 4;
    f32x4 acc[8];
#pragma unroll
    for (int t = 0; t < 8; t++) acc[t] = (f32x4){0.f, 0.f, 0.f, 0.f};
#pragma unroll
    for (int s = 0; s < 4; s++) {
        half8 a = *(const half8*)(A + (size_t)mload * 128 + s * 32 + kq * 8);
#pragma unroll
        for (int t = 0; t < 8; t++) {
            half8 bh = *(const half8*)(Wh + (size_t)((s * 8 + t) * 64 + lane) * 8);
            half8 bl = *(const half8*)(Wl + (size_t)((s * 8 + t) * 64 + lane) * 8);
            acc[t] = __builtin_amdgcn_mfma_f32_16x16x32_f16(a, bh, acc[t], 0, 0, 0);
            acc[t] = __builtin_amdgcn_mfma_f32_16x16x32_f16(a, bl, acc[t], 0, 0, 0);
        }
    }
    int coln = lane & 15;
    int rbase = mbase + ((lane >> 4) << 2);
#pragma unroll
    for (int t = 0; t < 8; t++) {
#pragma unroll
        for (int i = 0; i < 4; i++) {
            int rr = rbase + i;
            if (rr < M) H[(size_t)rr * 128 + t * 16 + coln] = (f16)acc[t][i];
        }
    }
}

// Layer 3: A f16 (pre-scaled) [M x 128] -> H3' f16 [M x 16].
__global__ __launch_bounds__(256) void gemm16(const f16* __restrict__ A,
                                              const f16* __restrict__ Wh,
                                              const f16* __restrict__ Wl,
                                              f16* __restrict__ H, int M) {
    int wave = threadIdx.x >> 6, lane = threadIdx.x & 63;
    int mbase = blockIdx.x * 64 + wave * 16;
    int mload = mbase + (lane & 15);
    if (mload >= M) mload = M - 1;
    int kq = lane >> 4;
    f32x4 acc = (f32x4){0.f, 0.f, 0.f, 0.f};
#pragma unroll
    for (int s = 0; s < 4; s++) {
        half8 a = *(const half8*)(A + (size_t)mload * 128 + s * 32 + kq * 8);
        half8 bh = *(const half8*)(Wh + (size_t)(s * 64 + lane) * 8);
        half8 bl = *(const half8*)(Wl + (size_t)(s * 64 + lane) * 8);
        acc = __builtin_amdgcn_mfma_f32_16x16x32_f16(a, bh, acc, 0, 0, 0);
        acc = __builtin_amdgcn_mfma_f32_16x16x32_f16(a, bl, acc, 0, 0, 0);
    }
    int coln = lane & 15;
    int rbase = mbase + ((lane >> 4) << 2);
#pragma unroll
    for (int i = 0; i < 4; i++) {
        int rr = rbase + i;
        if (rr < M) H[(size_t)rr * 16 + coln] = (f16)acc[i];
    }
}

// ---------------- aggregation ----------------
// One wave per row; lane handles features 2*lane, 2*lane+1 (half2, 4B/lane ->
// one coalesced 256B gather per edge). Unroll 16 for MLP.
// out = relu(dinv[r]*(sum h'[c] + h'[r]) + b) * dinv[r]   (h' pre-scaled).
__global__ __launch_bounds__(256) void agg128(const f16* __restrict__ h,
                                              const u32* __restrict__ ecol,
                                              const u32* __restrict__ row_start,
                                              const float* __restrict__ dinv,
                                              const float* __restrict__ bias,
                                              f16* __restrict__ out, int M) {
    int wave = threadIdx.x >> 6, lane = threadIdx.x & 63;
    int r = blockIdx.x * 4 + wave;
    if (r >= M) return;
    u32 beg = row_start[r], end = row_start[r + 1];
    const half2_t* hp = (const half2_t*)h;
    float ax0 = 0, ay0 = 0, ax1 = 0, ay1 = 0, ax2 = 0, ay2 = 0, ax3 = 0, ay3 = 0;
    u32 e = beg;
    for (; e + 16 <= end; e += 16) {
        u32 c[16];
#pragma unroll
        for (int j = 0; j < 16; j++) c[j] = ecol[e + j];
        half2_t v[16];
#pragma unroll
        for (int j = 0; j < 16; j++) v[j] = hp[(size_t)c[j] * 64 + lane];
#pragma unroll
        for (int j = 0; j < 16; j += 4) {
            ax0 += (float)v[j][0];     ay0 += (float)v[j][1];
            ax1 += (float)v[j + 1][0]; ay1 += (float)v[j + 1][1];
            ax2 += (float)v[j + 2][0]; ay2 += (float)v[j + 2][1];
            ax3 += (float)v[j + 3][0]; ay3 += (float)v[j + 3][1];
        }
    }
    for (; e + 4 <= end; e += 4) {
        u32 c0 = ecol[e], c1 = ecol[e + 1], c2 = ecol[e + 2], c3 = ecol[e + 3];
        half2_t v0 = hp[(size_t)c0 * 64 + lane];
        half2_t v1 = hp[(size_t)c1 * 64 + lane];
        half2_t v2 = hp[(size_t)c2 * 64 + lane];
        half2_t v3 = hp[(size_t)c3 * 64 + lane];
        ax0 += (float)v0[0]; ay0 += (float)v0[1];
        ax1 += (float)v1[0]; ay1 += (float)v1[1];
        ax2 += (float)v2[0]; ay2 += (float)v2[1];
        ax3 += (float)v3[0]; ay3 += (float)v3[1];
    }
    for (; e < end; ++e) {
        half2_t v = hp[(size_t)ecol[e] * 64 + lane];
        ax0 += (float)v[0]; ay0 += (float)v[1];
    }
    half2_t vs = hp[(size_t)r * 64 + lane];
    float dr = dinv[r];
    float2 bb = ((const float2*)bias)[lane];
    float ax = (((ax0 + ax1) + (ax2 + ax3)) + (float)vs[0]) * dr + bb.x;
    float ay = (((ay0 + ay1) + (ay2 + ay3)) + (float)vs[1]) * dr + bb.y;
    ax = fmaxf(ax, 0.f) * dr;  // pre-scale for next layer's gather
    ay = fmaxf(ay, 0.f) * dr;
    half2_t o;
    o[0] = (f16)ax;
    o[1] = (f16)ay;
    ((half2_t*)out)[(size_t)r * 64 + lane] = o;
}

// 16 lanes per row; h3' pre-scaled; fused bias + log_softmax; fp32 output.
__global__ __launch_bounds__(256) void agg16_lsm(const f16* __restrict__ h3,
                                                 const u32* __restrict__ ecol,
                                                 const u32* __restrict__ row_start,
                                                 const float* __restrict__ dinv,
                                                 const float* __restrict__ bias,
                                                 float* __restrict__ out, int M) {
    int g = threadIdx.x >> 4, l = threadIdx.x & 15;
    int r = blockIdx.x * 16 + g;
    if (r >= M) return;
    u32 beg = row_start[r], end = row_start[r + 1];
    float a0 = 0.f, a1 = 0.f, a2 = 0.f, a3 = 0.f;
    u32 e = beg;
    for (; e + 4 <= end; e += 4) {
        u32 c0 = ecol[e], c1 = ecol[e + 1], c2 = ecol[e + 2], c3 = ecol[e + 3];
        a0 += (float)h3[(size_t)c0 * 16 + l];
        a1 += (float)h3[(size_t)c1 * 16 + l];
        a2 += (float)h3[(size_t)c2 * 16 + l];
        a3 += (float)h3[(size_t)c3 * 16 + l];
    }
    for (; e < end; ++e) a0 += (float)h3[(size_t)ecol[e] * 16 + l];
    float dr = dinv[r];
    float acc = (((a0 + a1) + (a2 + a3)) + (float)h3[(size_t)r * 16 + l]) * dr +
                bias[l];
    float m = acc;
#pragma unroll
    for (int o = 8; o >= 1; o >>= 1) m = fmaxf(m, __shfl_xor(m, o, 16));
    float ex = expf(acc - m);
    float s = ex;
#pragma unroll
    for (int o = 8; o >= 1; o >>= 1) s += __shfl_xor(s, o, 16);
    out[(size_t)r * 16 + l] = acc - m - logf(s);
}

// ---------------- launch ----------------

extern "C" void kernel_launch(void* const* d_in, const int* in_sizes, int n_in,
                              void* d_out, int out_size, void* d_ws, size_t ws_size,
                              hipStream_t stream) {
    const float* x = (const float*)d_in[0];
    const int* ei = (const int*)d_in[1];
    const float* W1 = (const float*)d_in[2];
    const float* b1 = (const float*)d_in[3];
    const float* W2 = (const float*)d_in[4];
    const float* b2 = (const float*)d_in[5];
    const float* W3 = (const float*)d_in[6];
    const float* b3 = (const float*)d_in[7];
    int N = in_sizes[0] / D_IN;
    int E = in_sizes[1] / 2;

    int NBK = (N + RPB - 1) / RPB;     // 782 row-buckets (<= MAXBUCK)
    int NB = (E + CHUNK - 1) / CHUNK;  // 98 hist/scatter blocks
    int L = NBK * NB;                  // 76636 Hmat entries

    char* p = (char*)d_ws;
    auto alloc = [&](size_t bytes) -> void* {
        void* q = (void*)p;
        p += (bytes + 255) & ~(size_t)255;
        return q;
    };
    u32* flag = (u32*)alloc(256);
    float* dinv = (float*)alloc((size_t)N * 4);
    u32* row_start = (u32*)alloc((size_t)(N + 1) * 4);
    u32* partial2 = (u32*)alloc(4096);
    u32* Hmat = (u32*)alloc((size_t)(L + 1) * 4);
    u32* ecol = (u32*)alloc((size_t)E * 4);
    u32* bdata = (u32*)alloc((size_t)E * 4);
    f16* wf1h = (f16*)alloc(16384 * 2);
    f16* wf1l = (f16*)alloc(16384 * 2);
    f16* wf2h = (f16*)alloc(16384 * 2);
    f16* wf2l = (f16*)alloc(16384 * 2);
    f16* wf3h = (f16*)alloc(2048 * 2);
    f16* wf3l = (f16*)alloc(2048 * 2);
    f16* h = (f16*)alloc((size_t)N * 128 * 2);
    f16* act = (f16*)alloc((size_t)N * 128 * 2);
    f16* h3 = (f16*)alloc((size_t)N * 16 * 2);
    (void)ws_size; (void)n_in; (void)out_size;

    hipMemsetAsync(flag, 0, 4, stream);

    int nb2 = (L + 255) / 256;  // 300 <= 512 for scan2

    detect_k<<<32, 256, 0, stream>>>(ei, flag, 8192);
    hist_k<<<NB, 256, 0, stream>>>(ei, flag, Hmat, E, N, NBK, NB);
    scan1<<<nb2, 256, 0, stream>>>(Hmat, Hmat, partial2, L);
    scan2<<<1, 512, 0, stream>>>(partial2, nb2);
    scan3<<<nb2, 256, 0, stream>>>(Hmat, partial2, L, E);  // sentinel Hmat[L]=E
    scatter_bd<<<NB, 256, 0, stream>>>(ei, flag, Hmat, bdata, E, N, NBK, NB);
    finalize_k<<<NBK, 256, 0, stream>>>(bdata, Hmat, row_start, dinv, ecol,
                                        N, E, NB);

    reformat_all<<<17, 256, 0, stream>>>(W1, W2, W3, wf1h, wf1l, wf2h, wf2l,
                                         wf3h, wf3l);

    int gb = (N + 63) / 64;
    int ab = (N + 3) / 4;
    gemm128_l1<<<gb, 256, 0, stream>>>(x, wf1h, wf1l, dinv, h, N);
    agg128<<<ab, 256, 0, stream>>>(h, ecol, row_start, dinv, b1, act, N);
    gemm128_l2<<<gb, 256, 0, stream>>>(act, wf2h, wf2l, h, N);
    agg128<<<ab, 256, 0, stream>>>(h, ecol, row_start, dinv, b2, act, N);
    gemm16<<<gb, 256, 0, stream>>>(act, wf3h, wf3l, h3, N);
    agg16_lsm<<<(N + 15) / 16, 256, 0, stream>>>(h3, ecol, row_start, dinv, b3,
                                                 (float*)d_out, N);
}